// Round 3
// baseline (723.183 us; speedup 1.0000x reference)
//
#include <hip/hip_runtime.h>

#define CDIM 384
#define NPIX 3136          // 56*56
#define BB 8
#define NROW (BB * NPIX)   // 25088
#define HDIM 48
#define CMID 1536
#define BN_EPS 1e-5f
#define LN_EPS 1e-5f

typedef short s16x8 __attribute__((ext_vector_type(8)));
typedef float f32x4 __attribute__((ext_vector_type(4)));
typedef unsigned short u16;

__device__ __forceinline__ u16 f2bf(float f) {
    unsigned u = __builtin_bit_cast(unsigned, f);
    u = (u + 0x7FFFu + ((u >> 16) & 1u)) >> 16;
    return (u16)u;
}
__device__ __forceinline__ float bf2f(u16 h) {
    unsigned u = ((unsigned)h) << 16;
    return __builtin_bit_cast(float, u);
}
__device__ __forceinline__ float phi_act(float v) { return expf(0.5f * (2.f * v - v * v)); }
__device__ __forceinline__ float gelu_act(float v) { return 0.5f * v * (1.f + erff(v * 0.7071067811865476f)); }

#define GLL16(g, l) __builtin_amdgcn_global_load_lds( \
    (const __attribute__((address_space(1))) void*)(g), \
    (__attribute__((address_space(3))) void*)(l), 16, 0, 0)

// ---------------------------------------------------------------------------
// bf16 MFMA GEMM: C(MxN) = act( A(MxK) * Bw(NxK)^T + bias ) [+ res]
// Tile 128 x TN (TN = 64 or 128), BK=32, 256 thr = 4 waves (2x2).
// DOUBLE-BUFFERED: prefetch tile k+1 via global_load_lds right after the
// barrier, compute tile k; the next barrier's vmcnt(0) drain is covered by
// a full compute phase. One barrier per K-step.
// LDS chunk layout: 16B chunks, chunk = (row>>4)*64 + koct*16 + (row&15),
// so GLL dest = wave-uniform base + lane*16 and frag ds_read_b128 is
// conflict-free at base + lane*16.
// ---------------------------------------------------------------------------
template<int ACT, bool BIAS, bool RES, bool OBF, bool OF32, int TN>
__global__ __launch_bounds__(256) void gemm_mfma(
    const u16* __restrict__ A, const u16* __restrict__ Bw,
    u16* __restrict__ Cbf, float* __restrict__ Cf,
    const float* __restrict__ res, const float* __restrict__ bias,
    int N, int K)
{
    constexpr int NFR = TN / 32;                 // n-frags per wave
    __shared__ __align__(16) u16 Asb[2][4096];   // 8 KB per buffer
    __shared__ __align__(16) u16 Bsb[2][TN * 32];
    const int t  = threadIdx.x;
    const int wv = t >> 6, ln = t & 63;
    const int lm = ln & 15, lq = ln >> 4;
    const int wm = wv >> 1, wn = wv & 1;
    const int m0 = blockIdx.y << 7, n0 = blockIdx.x * TN;

    const u16* gA0 = A  + (long)(m0 + wv * 16 + lm) * K + lq * 8;
    const u16* gA1 = gA0 + (long)64 * K;
    const u16* gB0 = Bw + (long)(n0 + wv * 16 + lm) * K + lq * 8;
    const u16* gB1 = gB0 + (long)64 * K;         // TN==128 only

    f32x4 acc[4][NFR] = {};
    const int nk = K >> 5;

    // prologue: tile 0 into buffer 0
    GLL16(gA0, &Asb[0][wv * 512]);
    GLL16(gA1, &Asb[0][wv * 512 + 2048]);
    GLL16(gB0, &Bsb[0][wv * 512]);
    if constexpr (TN == 128) GLL16(gB1, &Bsb[0][wv * 512 + 2048]);

    for (int k = 0; k < nk; k++) {
        const int cur = k & 1;
        __syncthreads();                         // drains prefetch issued last iter
        if (k + 1 < nk) {
            const int nx = cur ^ 1;
            gA0 += 32; gA1 += 32; gB0 += 32;
            GLL16(gA0, &Asb[nx][wv * 512]);
            GLL16(gA1, &Asb[nx][wv * 512 + 2048]);
            GLL16(gB0, &Bsb[nx][wv * 512]);
            if constexpr (TN == 128) { gB1 += 32; GLL16(gB1, &Bsb[nx][wv * 512 + 2048]); }
        }
        s16x8 av[4], bv[NFR];
        #pragma unroll
        for (int mf = 0; mf < 4; mf++)
            av[mf] = *(const s16x8*)&Asb[cur][(wm * 256 + mf * 64 + ln) * 8];
        #pragma unroll
        for (int nf = 0; nf < NFR; nf++)
            bv[nf] = *(const s16x8*)&Bsb[cur][((TN == 128 ? wn * 256 : wn * 128) + nf * 64 + ln) * 8];
        #pragma unroll
        for (int mf = 0; mf < 4; mf++)
            #pragma unroll
            for (int nf = 0; nf < NFR; nf++)
                acc[mf][nf] = __builtin_amdgcn_mfma_f32_16x16x32_bf16(
                    av[mf], bv[nf], acc[mf][nf], 0, 0, 0);
    }

    // Epilogue. C/D layout: col = lane&15, row = (lane>>4)*4 + reg.
    #pragma unroll
    for (int nf = 0; nf < NFR; nf++) {
        const int gn = n0 + (TN == 128 ? wn * 64 : wn * 32) + nf * 16 + lm;
        const float bval = BIAS ? bias[gn] : 0.f;
        #pragma unroll
        for (int mf = 0; mf < 4; mf++) {
            const int gmb = m0 + wm * 64 + mf * 16 + lq * 4;
            #pragma unroll
            for (int r = 0; r < 4; r++) {
                float v = acc[mf][nf][r];
                if (BIAS) v += bval;
                if (ACT == 1) v = phi_act(v);
                else if (ACT == 2) v = gelu_act(v);
                const long off = (long)(gmb + r) * N + gn;
                if (RES) v += res[off];
                if (OF32) Cf[off] = v;
                if (OBF)  Cbf[off] = f2bf(v);
            }
        }
    }
}

// ---------------------------------------------------------------------------
// NCHW f32 -> NHWC f32 + bf16 (64x64 LDS tiles)
// ---------------------------------------------------------------------------
__global__ __launch_bounds__(256) void nchw_to_nhwc(const float* __restrict__ x,
                                                    float* __restrict__ of,
                                                    u16* __restrict__ ob)
{
    __shared__ float tile[64 * 65];
    const int n0 = blockIdx.x << 6, c0 = blockIdx.y << 6, b = blockIdx.z;
    const int t = threadIdx.x;
    const float* ip = x + ((long)b * CDIM + c0) * NPIX + n0;
    for (int idx = t; idx < 4096; idx += 256) {
        const int cc = idx >> 6, nn = idx & 63;
        tile[cc * 65 + nn] = ip[(long)cc * NPIX + nn];
    }
    __syncthreads();
    for (int idx = t; idx < 4096; idx += 256) {
        const int nn = idx >> 6, cc = idx & 63;
        const float v = tile[cc * 65 + nn];
        const long o = ((long)b * NPIX + n0 + nn) * CDIM + c0 + cc;
        of[o] = v; ob[o] = f2bf(v);
    }
}

// ---------------------------------------------------------------------------
// Depthwise 3x3 SAME, NHWC bf16.
// ---------------------------------------------------------------------------
__global__ __launch_bounds__(256) void dwconv_nhwc(const u16* __restrict__ in,
                                                   const u16* __restrict__ wt,
                                                   u16* __restrict__ out)
{
    const long tid = (long)blockIdx.x * 256 + threadIdx.x;
    const int c8 = (int)(tid % 48);
    const int p  = (int)((tid / 48) % NPIX);
    const int b  = (int)(tid / (48LL * NPIX));
    const int y = p / 56, x = p % 56;
    const u16* base = in + (long)b * NPIX * CDIM + c8 * 8;
    float acc[8] = {};
    #pragma unroll
    for (int r = 0; r < 3; r++) {
        const int yy = y + r - 1;
        if ((unsigned)yy >= 56u) continue;
        #pragma unroll
        for (int s = 0; s < 3; s++) {
            const int xx = x + s - 1;
            if ((unsigned)xx >= 56u) continue;
            const s16x8 iv = *(const s16x8*)&base[(long)(yy * 56 + xx) * CDIM];
            const s16x8 wv = *(const s16x8*)&wt[(r * 3 + s) * CDIM + c8 * 8];
            #pragma unroll
            for (int j = 0; j < 8; j++)
                acc[j] = fmaf(bf2f((u16)iv[j]), bf2f((u16)wv[j]), acc[j]);
        }
    }
    s16x8 ov;
    #pragma unroll
    for (int j = 0; j < 8; j++) ov[j] = (short)f2bf(acc[j]);
    *(s16x8*)&out[((long)b * NPIX + p) * CDIM + c8 * 8] = ov;
}

// ---------------------------------------------------------------------------
// kv[bh][d][e] = sum_n kp*v ; ksum[bh][d] = sum_n kp.
// ---------------------------------------------------------------------------
__global__ __launch_bounds__(256) void attn_kv_k(const u16* __restrict__ qk,
                                                 const u16* __restrict__ vb,
                                                 float* __restrict__ kv,
                                                 float* __restrict__ ksum)
{
    const int sp = blockIdx.x, bh = blockIdx.y;
    const int b = bh >> 3, h = bh & 7;
    const u16* kbase = qk + (long)b * NPIX * 768 + 384 + h * HDIM;
    const u16* vbase = vb + (long)b * NPIX * CDIM + h * HDIM;
    __shared__ float kt[64 * 48];
    __shared__ float vt[64 * 48];
    const int t = threadIdx.x;
    const int dg = t >> 4, eg = t & 15;
    float acc[3][3] = {};
    float ks[3] = {};
    for (int tl = sp; tl < 49; tl += 8) {
        const int n0 = tl << 6;
        __syncthreads();
        for (int idx = t; idx < 3072; idx += 256) {
            const int nn = idx / 48, d = idx % 48;
            kt[idx] = bf2f(kbase[(long)(n0 + nn) * 768 + d]);
            vt[idx] = bf2f(vbase[(long)(n0 + nn) * CDIM + d]);
        }
        __syncthreads();
        for (int nn = 0; nn < 64; nn++) {
            float kvv[3], vvv[3];
            #pragma unroll
            for (int i = 0; i < 3; i++) kvv[i] = kt[nn * 48 + dg * 3 + i];
            #pragma unroll
            for (int j = 0; j < 3; j++) vvv[j] = vt[nn * 48 + eg * 3 + j];
            #pragma unroll
            for (int i = 0; i < 3; i++)
                #pragma unroll
                for (int j = 0; j < 3; j++)
                    acc[i][j] = fmaf(kvv[i], vvv[j], acc[i][j]);
            if (eg == 0) {
                #pragma unroll
                for (int i = 0; i < 3; i++) ks[i] += kvv[i];
            }
        }
    }
    float* kvp = kv + (long)bh * HDIM * HDIM;
    #pragma unroll
    for (int i = 0; i < 3; i++)
        #pragma unroll
        for (int j = 0; j < 3; j++)
            atomicAdd(&kvp[(dg * 3 + i) * HDIM + eg * 3 + j], acc[i][j]);
    if (eg == 0) {
        #pragma unroll
        for (int i = 0; i < 3; i++) atomicAdd(&ksum[bh * HDIM + dg * 3 + i], ks[i]);
    }
}

// ---------------------------------------------------------------------------
// out[n][h*48+e] = (sum_d qp*kv) / (qp . ksum + eps)
// ---------------------------------------------------------------------------
__global__ __launch_bounds__(256) void attn_out_k(const u16* __restrict__ qk,
                                                  const float* __restrict__ kv,
                                                  const float* __restrict__ ksum,
                                                  u16* __restrict__ outb)
{
    const int bh = blockIdx.y, b = bh >> 3, h = bh & 7;
    const int n0 = blockIdx.x << 6;
    const u16* qbase = qk + (long)b * NPIX * 768 + h * HDIM;
    __shared__ float qt[64 * 48];
    __shared__ float kvs[48 * 48];
    __shared__ float kss[48];
    const int t = threadIdx.x;
    for (int idx = t; idx < 3072; idx += 256) {
        const int nn = idx / 48, d = idx % 48;
        qt[idx] = bf2f(qbase[(long)(n0 + nn) * 768 + d]);
    }
    for (int idx = t; idx < 2304; idx += 256) kvs[idx] = kv[(long)bh * HDIM * HDIM + idx];
    if (t < 48) kss[t] = ksum[bh * HDIM + t];
    __syncthreads();
    const int nn = t & 63, eg = t >> 6;
    float a[12] = {};
    float dot = 0.f;
    for (int d = 0; d < 48; d++) {
        const float qd = qt[nn * 48 + d];
        dot = fmaf(qd, kss[d], dot);
        const float* kr = &kvs[d * 48 + eg * 12];
        #pragma unroll
        for (int e = 0; e < 12; e++) a[e] = fmaf(qd, kr[e], a[e]);
    }
    const float z = 1.f / (dot + 1e-6f);
    u16* op = outb + ((long)b * NPIX + n0 + nn) * CDIM + h * HDIM + eg * 12;
    #pragma unroll
    for (int e = 0; e < 12; e++) op[e] = f2bf(a[e] * z);
}

// ---------------------------------------------------------------------------
// LayerNorm over contiguous 384 channels (NHWC)
// ---------------------------------------------------------------------------
__global__ __launch_bounds__(256) void ln_k(const float* __restrict__ x2,
                                            const float* __restrict__ lw,
                                            const float* __restrict__ lb,
                                            u16* __restrict__ xn)
{
    const int row = blockIdx.x * 4 + (threadIdx.x >> 6);
    const int lane = threadIdx.x & 63;
    const float* rp = x2 + (long)row * CDIM;
    float2 v[3];
    float sum = 0.f, sq = 0.f;
    #pragma unroll
    for (int i = 0; i < 3; i++) {
        v[i] = *(const float2*)&rp[lane * 2 + i * 128];
        sum += v[i].x + v[i].y;
        sq = fmaf(v[i].x, v[i].x, fmaf(v[i].y, v[i].y, sq));
    }
    #pragma unroll
    for (int off = 1; off < 64; off <<= 1) {
        sum += __shfl_xor(sum, off);
        sq  += __shfl_xor(sq, off);
    }
    const float mu = sum * (1.f / CDIM);
    const float rs = rsqrtf(sq * (1.f / CDIM) - mu * mu + LN_EPS);
    u16* op = xn + (long)row * CDIM;
    #pragma unroll
    for (int i = 0; i < 3; i++) {
        const int c = lane * 2 + i * 128;
        op[c]     = f2bf((v[i].x - mu) * rs * lw[c] + lb[c]);
        op[c + 1] = f2bf((v[i].y - mu) * rs * lw[c + 1] + lb[c + 1]);
    }
}

// ---------------------------------------------------------------------------
// d_out NCHW = transpose(x2 + mlp) from NHWC f32
// ---------------------------------------------------------------------------
__global__ __launch_bounds__(256) void final_out(const float* __restrict__ x2,
                                                 const float* __restrict__ mlp,
                                                 float* __restrict__ out)
{
    __shared__ float tile[64 * 65];
    const int n0 = blockIdx.x << 6, c0 = blockIdx.y << 6, b = blockIdx.z;
    const int t = threadIdx.x;
    for (int idx = t; idx < 4096; idx += 256) {
        const int nn = idx >> 6, cc = idx & 63;
        const long o = ((long)b * NPIX + n0 + nn) * CDIM + c0 + cc;
        tile[nn * 65 + cc] = x2[o] + mlp[o];
    }
    __syncthreads();
    float* op = out + ((long)b * CDIM + c0) * NPIX + n0;
    for (int idx = t; idx < 4096; idx += 256) {
        const int cc = idx >> 6, nn = idx & 63;
        op[(long)cc * NPIX + nn] = tile[nn * 65 + cc];
    }
}

// ---------------------------------------------------------------------------
// Prep kernels
// ---------------------------------------------------------------------------
__global__ void prep_bn_k(const float* __restrict__ w1, const float* __restrict__ b1,
                          const float* __restrict__ m1, const float* __restrict__ v1,
                          const float* __restrict__ w2, const float* __restrict__ b2,
                          const float* __restrict__ m2, const float* __restrict__ v2,
                          const float* __restrict__ db,
                          float* s1, float* t1, float* s2, float* t2)
{
    const int i = threadIdx.x;
    if (i < CDIM) {
        const float a = w1[i] * rsqrtf(v1[i] + BN_EPS);
        s1[i] = a; t1[i] = b1[i] - m1[i] * a;
        const float c = w2[i] * rsqrtf(v2[i] + BN_EPS);
        s2[i] = c; t2[i] = b2[i] - m2[i] * c + db[i] * c;
    }
}

__global__ __launch_bounds__(64) void prep_w_k(
    const float* __restrict__ cw1, const float* __restrict__ cb1,
    const float* __restrict__ cw2, const float* __restrict__ cb2,
    const float* __restrict__ s1, const float* __restrict__ t1,
    const float* __restrict__ s2, const float* __restrict__ t2,
    u16* __restrict__ w1e, float* __restrict__ b1e,
    u16* __restrict__ w2e, float* __restrict__ b2e)
{
    const int o = blockIdx.x;
    const bool sec = (o >= CDIM);
    const int oo = sec ? o - CDIM : o;
    const float* cw = sec ? cw2 : cw1;
    const float* cb = sec ? cb2 : cb1;
    const float* s  = sec ? s2  : s1;
    const float* tt = sec ? t2  : t1;
    u16* we = sec ? w2e : w1e;
    float* be = sec ? b2e : b1e;
    float part = 0.f;
    for (int i = threadIdx.x; i < CDIM; i += 64) {
        const float wv = cw[oo * CDIM + i];
        we[oo * CDIM + i] = f2bf(wv * s[i]);
        part += wv * tt[i];
    }
    for (int off = 32; off; off >>= 1) part += __shfl_down(part, off);
    if (threadIdx.x == 0) be[oo] = cb[oo] + part;
}

__global__ void cvt_k(const float* __restrict__ in, u16* __restrict__ out, int n)
{
    const int i = blockIdx.x * 256 + threadIdx.x;
    if (i < n) out[i] = f2bf(in[i]);
}

__global__ __launch_bounds__(256) void transcvt_k(const float* __restrict__ in,
                                                  u16* __restrict__ out, int R, int C)
{
    __shared__ float tile[64 * 65];
    const int c0 = blockIdx.x << 6, r0 = blockIdx.y << 6;
    const int t = threadIdx.x;
    for (int idx = t; idx < 4096; idx += 256) {
        const int rr = idx >> 6, cc = idx & 63;
        tile[rr * 65 + cc] = in[(long)(r0 + rr) * C + c0 + cc];
    }
    __syncthreads();
    for (int idx = t; idx < 4096; idx += 256) {
        const int cc = idx >> 6, rr = idx & 63;
        out[(long)(c0 + cc) * R + r0 + rr] = f2bf(tile[rr * 65 + cc]);
    }
}

__global__ void dwt_k(const float* __restrict__ dw, u16* __restrict__ o)
{
    const int i = blockIdx.x * 256 + threadIdx.x;
    if (i < 9 * CDIM) {
        const int c = i / 9, tap = i % 9;
        o[tap * CDIM + c] = f2bf(dw[i]);
    }
}

// ---------------------------------------------------------------------------
// Launch
// ---------------------------------------------------------------------------
extern "C" void kernel_launch(void* const* d_in, const int* in_sizes, int n_in,
                              void* d_out, int out_size, void* d_ws, size_t ws_size,
                              hipStream_t stream)
{
    const float* x      = (const float*)d_in[0];
    const float* bn1_w  = (const float*)d_in[1];
    const float* bn1_b  = (const float*)d_in[2];
    const float* bn1_m  = (const float*)d_in[3];
    const float* bn1_v  = (const float*)d_in[4];
    const float* cw1    = (const float*)d_in[5];
    const float* cb1    = (const float*)d_in[6];
    const float* dwW    = (const float*)d_in[7];
    const float* db     = (const float*)d_in[8];
    const float* bn2_w  = (const float*)d_in[9];
    const float* bn2_b  = (const float*)d_in[10];
    const float* bn2_m  = (const float*)d_in[11];
    const float* bn2_v  = (const float*)d_in[12];
    const float* cw2    = (const float*)d_in[13];
    const float* cb2    = (const float*)d_in[14];
    const float* qkv_w  = (const float*)d_in[15];
    const float* proj_w = (const float*)d_in[16];
    const float* proj_b = (const float*)d_in[17];
    const float* ln_w   = (const float*)d_in[18];
    const float* ln_b   = (const float*)d_in[19];
    const float* mlp_w1 = (const float*)d_in[20];
    const float* mlp_b1 = (const float*)d_in[21];
    const float* mlp_w2 = (const float*)d_in[22];
    const float* mlp_b2 = (const float*)d_in[23];
    float* outF = (float*)d_out;

    const long S = (long)NROW * CDIM;   // 9,633,792
    float* wsf = (float*)d_ws;

    // fp32 slots (time-aliased) — identical map to Round 2 (proven)
    float* xh_f  = wsf;                       // F0: NHWC x (dead after g2)
    float* x2_f  = wsf;                       // F0: x2 (born g4)
    u16*   v_bf  = (u16*)wsf;                 // F0 during attention (v)
    float* x1_f  = wsf + S;                   // F1: x1 (dead after g4)
    u16*   hmid  = (u16*)(wsf + S);           // F1: mlp hidden half
    u16* ar   = (u16*)(wsf + 2 * S);
    u16* a0   = ar;                           // xh_bf -> x1_bf -> attn_bf -> xn_bf
    u16* a1   = ar + S;                       // h_bf -> qk_bf (spans a1..a2)
    u16* a2   = ar + 2 * S;                   // d_bf
    float* mlp_f = (float*)(ar + S);          // mlp out f32
    u16* wtb   = (u16*)(wsf + 3 * S + S / 2);
    u16* w1e   = wtb;
    u16* w2e   = w1e + CDIM * CDIM;
    u16* qkvw  = w2e + CDIM * CDIM;
    u16* projw = qkvw + 1152 * CDIM;
    u16* mw1t  = projw + CDIM * CDIM;
    u16* mw2t  = mw1t + CMID * CDIM;
    u16* dwt   = mw2t + CDIM * CMID;
    float* fb  = (float*)(dwt + 9 * CDIM);
    float* b1e = fb;
    float* b2e = b1e + CDIM;
    float* s1  = b2e + CDIM;
    float* t1  = s1 + CDIM;
    float* s2  = t1 + CDIM;
    float* t2  = s2 + CDIM;
    float* kvb = t2 + CDIM;
    float* ksb = kvb + 64 * HDIM * HDIM;

    // --- weight prep ---
    prep_bn_k<<<1, CDIM, 0, stream>>>(bn1_w, bn1_b, bn1_m, bn1_v,
                                      bn2_w, bn2_b, bn2_m, bn2_v, db, s1, t1, s2, t2);
    prep_w_k<<<2 * CDIM, 64, 0, stream>>>(cw1, cb1, cw2, cb2, s1, t1, s2, t2,
                                          w1e, b1e, w2e, b2e);
    cvt_k<<<(1152 * CDIM + 255) / 256, 256, 0, stream>>>(qkv_w, qkvw, 1152 * CDIM);
    cvt_k<<<(CDIM * CDIM + 255) / 256, 256, 0, stream>>>(proj_w, projw, CDIM * CDIM);
    transcvt_k<<<dim3(CMID / 64, CDIM / 64), 256, 0, stream>>>(mlp_w1, mw1t, CDIM, CMID);
    transcvt_k<<<dim3(CDIM / 64, CMID / 64), 256, 0, stream>>>(mlp_w2, mw2t, CMID, CDIM);
    dwt_k<<<(9 * CDIM + 255) / 256, 256, 0, stream>>>(dwW, dwt);

    // --- pipeline (all NHWC) ---
    nchw_to_nhwc<<<dim3(49, 6, 8), 256, 0, stream>>>(x, xh_f, a0);
    // g1: h = conv1(x)   [TN=64 -> 1176 blocks]
    gemm_mfma<0, true, false, true, false, 64><<<dim3(6, 196), 256, 0, stream>>>(
        a0, w1e, a1, nullptr, nullptr, b1e, CDIM, CDIM);
    dwconv_nhwc<<<(int)((long)BB * NPIX * 48 / 256), 256, 0, stream>>>(a1, dwt, a2);
    // g2: x1 = conv2(d) + x
    gemm_mfma<0, true, true, true, true, 64><<<dim3(6, 196), 256, 0, stream>>>(
        a2, w2e, a0, x1_f, xh_f, b2e, CDIM, CDIM);
    // g3a: qk = phi(Wqk x1) ; g3b: v = Wv x1
    gemm_mfma<1, false, false, true, false, 128><<<dim3(6, 196), 256, 0, stream>>>(
        a0, qkvw, a1, nullptr, nullptr, nullptr, 768, CDIM);
    gemm_mfma<0, false, false, true, false, 64><<<dim3(6, 196), 256, 0, stream>>>(
        a0, qkvw + 768 * CDIM, v_bf, nullptr, nullptr, nullptr, CDIM, CDIM);
    // attention
    hipMemsetAsync(kvb, 0, (size_t)(64 * HDIM * HDIM + 64 * HDIM) * sizeof(float), stream);
    attn_kv_k<<<dim3(8, 64), 256, 0, stream>>>(a1, v_bf, kvb, ksb);
    attn_out_k<<<dim3(49, 64), 256, 0, stream>>>(a1, kvb, ksb, a0);
    // g4: x2 = proj(attn) + x1
    gemm_mfma<0, true, true, false, true, 64><<<dim3(6, 196), 256, 0, stream>>>(
        a0, projw, nullptr, x2_f, x1_f, proj_b, CDIM, CDIM);
    // LN -> xn (bf16)
    ln_k<<<NROW / 4, 256, 0, stream>>>(x2_f, ln_w, ln_b, a0);
    // MLP in two M-halves
    const long RH = (long)NROW / 2;   // 12544
    gemm_mfma<2, true, false, true, false, 128><<<dim3(12, 98), 256, 0, stream>>>(
        a0, mw1t, hmid, nullptr, nullptr, mlp_b1, CMID, CDIM);
    gemm_mfma<0, true, false, false, true, 64><<<dim3(6, 98), 256, 0, stream>>>(
        hmid, mw2t, nullptr, mlp_f, nullptr, mlp_b2, CDIM, CMID);
    gemm_mfma<2, true, false, true, false, 128><<<dim3(12, 98), 256, 0, stream>>>(
        a0 + RH * CDIM, mw1t, hmid, nullptr, nullptr, mlp_b1, CMID, CDIM);
    gemm_mfma<0, true, false, false, true, 64><<<dim3(6, 98), 256, 0, stream>>>(
        hmid, mw2t, nullptr, mlp_f + RH * CDIM, nullptr, mlp_b2, CDIM, CMID);
    // final: d_out = NCHW(x2 + mlp)
    final_out<<<dim3(49, 6, 8), 256, 0, stream>>>(x2_f, mlp_f, outF);
}

// Round 4
// 686.770 us; speedup vs baseline: 1.0530x; 1.0530x over previous
//
#include <hip/hip_runtime.h>

#define CDIM 384
#define NPIX 3136          // 56*56
#define BB 8
#define NROW (BB * NPIX)   // 25088
#define HDIM 48
#define CMID 1536
#define BN_EPS 1e-5f
#define LN_EPS 1e-5f

typedef short s16x8 __attribute__((ext_vector_type(8)));
typedef float f32x4 __attribute__((ext_vector_type(4)));
typedef unsigned short u16;

__device__ __forceinline__ u16 f2bf(float f) {
    unsigned u = __builtin_bit_cast(unsigned, f);
    u = (u + 0x7FFFu + ((u >> 16) & 1u)) >> 16;
    return (u16)u;
}
__device__ __forceinline__ float bf2f(u16 h) {
    unsigned u = ((unsigned)h) << 16;
    return __builtin_bit_cast(float, u);
}
__device__ __forceinline__ float phi_act(float v) { return expf(0.5f * (2.f * v - v * v)); }
__device__ __forceinline__ float gelu_act(float v) { return 0.5f * v * (1.f + erff(v * 0.7071067811865476f)); }

#define GLL16(g, l) __builtin_amdgcn_global_load_lds( \
    (const __attribute__((address_space(1))) void*)(g), \
    (__attribute__((address_space(3))) void*)(l), 16, 0, 0)

// ---------------------------------------------------------------------------
// bf16 MFMA GEMM: C(MxN) = act( A(MxK) * Bw(NxK)^T + bias ) [+ res]
// Tile 128 x TN, BK=32, 256 thr = 4 waves (2x2), double-buffered k-loop.
// NEW: bf16 outputs go through a per-wave LDS staging pass so global stores
// are 16B/lane fully-coalesced (128B segments) instead of 32B row fragments
// (which caused HBM RMW: WRITE 2x, FETCH +1x — R3 counters).
// QKV mode: N=1152 fused q|k|v; tiles with n0<768 -> Cbf (ld 768, phi),
// else -> Cv (ld 384, no act). 768 % 128 == 0 so selection is block-uniform.
// ---------------------------------------------------------------------------
template<int ACT, bool BIAS, bool RES, bool OBF, bool OF32, int TN, bool QKV>
__global__ __launch_bounds__(256) void gemm_mfma(
    const u16* __restrict__ A, const u16* __restrict__ Bw,
    u16* __restrict__ Cbf, u16* __restrict__ Cv, float* __restrict__ Cf,
    const float* __restrict__ res, const float* __restrict__ bias,
    int N, int K)
{
    constexpr int NFR = TN / 32;                 // n-frags per wave
    constexpr int TNw = TN / 2;                  // cols per wave
    constexpr int STR = TNw + 4;                 // staging row stride (u16)
    constexpr int KLOOP_U16 = 8192 + TN * 64;    // dbuf A (2x4096) + dbuf B
    constexpr int STG_U16 = 4 * 64 * STR;
    constexpr int SMEM_N = KLOOP_U16 > STG_U16 ? KLOOP_U16 : STG_U16;
    __shared__ __align__(16) u16 smem[SMEM_N];
    u16* Asb = smem;           // [2][4096]
    u16* Bsb = smem + 8192;    // [2][TN*32]

    const int t  = threadIdx.x;
    const int wv = t >> 6, ln = t & 63;
    const int lm = ln & 15, lq = ln >> 4;
    const int wm = wv >> 1, wn = wv & 1;
    const int m0 = blockIdx.y << 7, n0 = blockIdx.x * TN;

    const u16* gA0 = A  + (long)(m0 + wv * 16 + lm) * K + lq * 8;
    const u16* gA1 = gA0 + (long)64 * K;
    const u16* gB0 = Bw + (long)(n0 + wv * 16 + lm) * K + lq * 8;
    const u16* gB1 = gB0 + (long)64 * K;         // TN==128 only

    f32x4 acc[4][NFR] = {};
    const int nk = K >> 5;

    GLL16(gA0, &Asb[wv * 512]);
    GLL16(gA1, &Asb[wv * 512 + 2048]);
    GLL16(gB0, &Bsb[wv * 512]);
    if constexpr (TN == 128) GLL16(gB1, &Bsb[wv * 512 + 2048]);

    for (int k = 0; k < nk; k++) {
        const int cur = k & 1;
        __syncthreads();
        if (k + 1 < nk) {
            const int nx = cur ^ 1;
            gA0 += 32; gA1 += 32; gB0 += 32;
            GLL16(gA0, &Asb[nx * 4096 + wv * 512]);
            GLL16(gA1, &Asb[nx * 4096 + wv * 512 + 2048]);
            GLL16(gB0, &Bsb[nx * TN * 32 + wv * 512]);
            if constexpr (TN == 128) { gB1 += 32; GLL16(gB1, &Bsb[nx * TN * 32 + wv * 512 + 2048]); }
        }
        s16x8 av[4], bv[NFR];
        #pragma unroll
        for (int mf = 0; mf < 4; mf++)
            av[mf] = *(const s16x8*)&Asb[cur * 4096 + (wm * 256 + mf * 64 + ln) * 8];
        #pragma unroll
        for (int nf = 0; nf < NFR; nf++)
            bv[nf] = *(const s16x8*)&Bsb[cur * TN * 32 + ((TN == 128 ? wn * 256 : wn * 128) + nf * 64 + ln) * 8];
        #pragma unroll
        for (int mf = 0; mf < 4; mf++)
            #pragma unroll
            for (int nf = 0; nf < NFR; nf++)
                acc[mf][nf] = __builtin_amdgcn_mfma_f32_16x16x32_bf16(
                    av[mf], bv[nf], acc[mf][nf], 0, 0, 0);
    }

    // ---- epilogue ----
    // region select (QKV): block-uniform
    u16* obase = Cbf; int oldc = N; int ocol0 = n0;
    bool qk_phi = false;
    if constexpr (QKV) {
        if (n0 < 768) { obase = Cbf; oldc = 768; ocol0 = n0; qk_phi = true; }
        else          { obase = Cv;  oldc = 384; ocol0 = n0 - 768; }
    }

    if constexpr (OBF || QKV) {
        __syncthreads();                    // k-loop LDS dead; reuse as staging
        u16* stg = smem + wv * (64 * STR);
        #pragma unroll
        for (int nf = 0; nf < NFR; nf++) {
            const int lc = nf * 16 + lm;                // col within wave
            const int gn = n0 + wn * TNw + lc;          // logical col
            const float bval = BIAS ? bias[gn] : 0.f;
            #pragma unroll
            for (int mf = 0; mf < 4; mf++) {
                #pragma unroll
                for (int r = 0; r < 4; r++) {
                    const int lr = mf * 16 + lq * 4 + r;        // row within wave
                    float v = acc[mf][nf][r];
                    if (BIAS) v += bval;
                    if (ACT == 1) v = phi_act(v);
                    else if (ACT == 2) v = gelu_act(v);
                    if (QKV) { if (qk_phi) v = phi_act(v); }
                    const long off = (long)(m0 + wm * 64 + lr) * N + gn;
                    if (RES) v += res[off];
                    if (OF32) Cf[off] = v;
                    stg[lr * STR + lc] = f2bf(v);
                }
            }
        }
        __syncthreads();                    // drain ds_writes (wave-local suffices, barrier is safe)
        constexpr int CPR = TNw / 8;        // 16B chunks per row (8 or 4)
        constexpr int RPI = 64 / CPR;       // rows per store instr (8 or 16)
        const int cg = ln % CPR, rb = ln / CPR;
        #pragma unroll
        for (int it = 0; it < 64 / RPI; it++) {
            const int row = it * RPI + rb;
            const s16x8 vv = *(const s16x8*)&stg[row * STR + cg * 8];
            *(s16x8*)&obase[(long)(m0 + wm * 64 + row) * oldc + ocol0 + wn * TNw + cg * 8] = vv;
        }
    } else {
        // f32-only outputs: direct stores are 64B segments — already fine.
        #pragma unroll
        for (int nf = 0; nf < NFR; nf++) {
            const int gn = n0 + wn * TNw + nf * 16 + lm;
            const float bval = BIAS ? bias[gn] : 0.f;
            #pragma unroll
            for (int mf = 0; mf < 4; mf++) {
                const int gmb = m0 + wm * 64 + mf * 16 + lq * 4;
                #pragma unroll
                for (int r = 0; r < 4; r++) {
                    float v = acc[mf][nf][r];
                    if (BIAS) v += bval;
                    if (ACT == 1) v = phi_act(v);
                    else if (ACT == 2) v = gelu_act(v);
                    const long off = (long)(gmb + r) * N + gn;
                    if (RES) v += res[off];
                    Cf[off] = v;
                }
            }
        }
    }
}

// ---------------------------------------------------------------------------
// NCHW f32 -> NHWC f32 + bf16 (64x64 LDS tiles)
// ---------------------------------------------------------------------------
__global__ __launch_bounds__(256) void nchw_to_nhwc(const float* __restrict__ x,
                                                    float* __restrict__ of,
                                                    u16* __restrict__ ob)
{
    __shared__ float tile[64 * 65];
    const int n0 = blockIdx.x << 6, c0 = blockIdx.y << 6, b = blockIdx.z;
    const int t = threadIdx.x;
    const float* ip = x + ((long)b * CDIM + c0) * NPIX + n0;
    for (int idx = t; idx < 4096; idx += 256) {
        const int cc = idx >> 6, nn = idx & 63;
        tile[cc * 65 + nn] = ip[(long)cc * NPIX + nn];
    }
    __syncthreads();
    for (int idx = t; idx < 4096; idx += 256) {
        const int nn = idx >> 6, cc = idx & 63;
        const float v = tile[cc * 65 + nn];
        const long o = ((long)b * NPIX + n0 + nn) * CDIM + c0 + cc;
        of[o] = v; ob[o] = f2bf(v);
    }
}

// ---------------------------------------------------------------------------
// Depthwise 3x3 SAME, NHWC bf16.
// ---------------------------------------------------------------------------
__global__ __launch_bounds__(256) void dwconv_nhwc(const u16* __restrict__ in,
                                                   const u16* __restrict__ wt,
                                                   u16* __restrict__ out)
{
    const long tid = (long)blockIdx.x * 256 + threadIdx.x;
    const int c8 = (int)(tid % 48);
    const int p  = (int)((tid / 48) % NPIX);
    const int b  = (int)(tid / (48LL * NPIX));
    const int y = p / 56, x = p % 56;
    const u16* base = in + (long)b * NPIX * CDIM + c8 * 8;
    float acc[8] = {};
    #pragma unroll
    for (int r = 0; r < 3; r++) {
        const int yy = y + r - 1;
        if ((unsigned)yy >= 56u) continue;
        #pragma unroll
        for (int s = 0; s < 3; s++) {
            const int xx = x + s - 1;
            if ((unsigned)xx >= 56u) continue;
            const s16x8 iv = *(const s16x8*)&base[(long)(yy * 56 + xx) * CDIM];
            const s16x8 wv = *(const s16x8*)&wt[(r * 3 + s) * CDIM + c8 * 8];
            #pragma unroll
            for (int j = 0; j < 8; j++)
                acc[j] = fmaf(bf2f((u16)iv[j]), bf2f((u16)wv[j]), acc[j]);
        }
    }
    s16x8 ov;
    #pragma unroll
    for (int j = 0; j < 8; j++) ov[j] = (short)f2bf(acc[j]);
    *(s16x8*)&out[((long)b * NPIX + p) * CDIM + c8 * 8] = ov;
}

// ---------------------------------------------------------------------------
// kv[bh][d][e] = sum_n kp*v ; ksum[bh][d] = sum_n kp.
// ---------------------------------------------------------------------------
__global__ __launch_bounds__(256) void attn_kv_k(const u16* __restrict__ qk,
                                                 const u16* __restrict__ vb,
                                                 float* __restrict__ kv,
                                                 float* __restrict__ ksum)
{
    const int sp = blockIdx.x, bh = blockIdx.y;
    const int b = bh >> 3, h = bh & 7;
    const u16* kbase = qk + (long)b * NPIX * 768 + 384 + h * HDIM;
    const u16* vbase = vb + (long)b * NPIX * CDIM + h * HDIM;
    __shared__ float kt[64 * 48];
    __shared__ float vt[64 * 48];
    const int t = threadIdx.x;
    const int dg = t >> 4, eg = t & 15;
    float acc[3][3] = {};
    float ks[3] = {};
    for (int tl = sp; tl < 49; tl += 8) {
        const int n0 = tl << 6;
        __syncthreads();
        for (int idx = t; idx < 3072; idx += 256) {
            const int nn = idx / 48, d = idx % 48;
            kt[idx] = bf2f(kbase[(long)(n0 + nn) * 768 + d]);
            vt[idx] = bf2f(vbase[(long)(n0 + nn) * CDIM + d]);
        }
        __syncthreads();
        for (int nn = 0; nn < 64; nn++) {
            float kvv[3], vvv[3];
            #pragma unroll
            for (int i = 0; i < 3; i++) kvv[i] = kt[nn * 48 + dg * 3 + i];
            #pragma unroll
            for (int j = 0; j < 3; j++) vvv[j] = vt[nn * 48 + eg * 3 + j];
            #pragma unroll
            for (int i = 0; i < 3; i++)
                #pragma unroll
                for (int j = 0; j < 3; j++)
                    acc[i][j] = fmaf(kvv[i], vvv[j], acc[i][j]);
            if (eg == 0) {
                #pragma unroll
                for (int i = 0; i < 3; i++) ks[i] += kvv[i];
            }
        }
    }
    float* kvp = kv + (long)bh * HDIM * HDIM;
    #pragma unroll
    for (int i = 0; i < 3; i++)
        #pragma unroll
        for (int j = 0; j < 3; j++)
            atomicAdd(&kvp[(dg * 3 + i) * HDIM + eg * 3 + j], acc[i][j]);
    if (eg == 0) {
        #pragma unroll
        for (int i = 0; i < 3; i++) atomicAdd(&ksum[bh * HDIM + dg * 3 + i], ks[i]);
    }
}

// ---------------------------------------------------------------------------
// out[n][h*48+e] = (sum_d qp*kv) / (qp . ksum + eps)
// ---------------------------------------------------------------------------
__global__ __launch_bounds__(256) void attn_out_k(const u16* __restrict__ qk,
                                                  const float* __restrict__ kv,
                                                  const float* __restrict__ ksum,
                                                  u16* __restrict__ outb)
{
    const int bh = blockIdx.y, b = bh >> 3, h = bh & 7;
    const int n0 = blockIdx.x << 6;
    const u16* qbase = qk + (long)b * NPIX * 768 + h * HDIM;
    __shared__ float qt[64 * 48];
    __shared__ float kvs[48 * 48];
    __shared__ float kss[48];
    const int t = threadIdx.x;
    for (int idx = t; idx < 3072; idx += 256) {
        const int nn = idx / 48, d = idx % 48;
        qt[idx] = bf2f(qbase[(long)(n0 + nn) * 768 + d]);
    }
    for (int idx = t; idx < 2304; idx += 256) kvs[idx] = kv[(long)bh * HDIM * HDIM + idx];
    if (t < 48) kss[t] = ksum[bh * HDIM + t];
    __syncthreads();
    const int nn = t & 63, eg = t >> 6;
    float a[12] = {};
    float dot = 0.f;
    for (int d = 0; d < 48; d++) {
        const float qd = qt[nn * 48 + d];
        dot = fmaf(qd, kss[d], dot);
        const float* kr = &kvs[d * 48 + eg * 12];
        #pragma unroll
        for (int e = 0; e < 12; e++) a[e] = fmaf(qd, kr[e], a[e]);
    }
    const float z = 1.f / (dot + 1e-6f);
    u16* op = outb + ((long)b * NPIX + n0 + nn) * CDIM + h * HDIM + eg * 12;
    #pragma unroll
    for (int e = 0; e < 12; e++) op[e] = f2bf(a[e] * z);
}

// ---------------------------------------------------------------------------
// LayerNorm over contiguous 384 channels (NHWC)
// ---------------------------------------------------------------------------
__global__ __launch_bounds__(256) void ln_k(const float* __restrict__ x2,
                                            const float* __restrict__ lw,
                                            const float* __restrict__ lb,
                                            u16* __restrict__ xn)
{
    const int row = blockIdx.x * 4 + (threadIdx.x >> 6);
    const int lane = threadIdx.x & 63;
    const float* rp = x2 + (long)row * CDIM;
    float2 v[3];
    float sum = 0.f, sq = 0.f;
    #pragma unroll
    for (int i = 0; i < 3; i++) {
        v[i] = *(const float2*)&rp[lane * 2 + i * 128];
        sum += v[i].x + v[i].y;
        sq = fmaf(v[i].x, v[i].x, fmaf(v[i].y, v[i].y, sq));
    }
    #pragma unroll
    for (int off = 1; off < 64; off <<= 1) {
        sum += __shfl_xor(sum, off);
        sq  += __shfl_xor(sq, off);
    }
    const float mu = sum * (1.f / CDIM);
    const float rs = rsqrtf(sq * (1.f / CDIM) - mu * mu + LN_EPS);
    u16* op = xn + (long)row * CDIM;
    #pragma unroll
    for (int i = 0; i < 3; i++) {
        const int c = lane * 2 + i * 128;
        op[c]     = f2bf((v[i].x - mu) * rs * lw[c] + lb[c]);
        op[c + 1] = f2bf((v[i].y - mu) * rs * lw[c + 1] + lb[c + 1]);
    }
}

// ---------------------------------------------------------------------------
// d_out NCHW = transpose(x2 + mlp) from NHWC f32
// ---------------------------------------------------------------------------
__global__ __launch_bounds__(256) void final_out(const float* __restrict__ x2,
                                                 const float* __restrict__ mlp,
                                                 float* __restrict__ out)
{
    __shared__ float tile[64 * 65];
    const int n0 = blockIdx.x << 6, c0 = blockIdx.y << 6, b = blockIdx.z;
    const int t = threadIdx.x;
    for (int idx = t; idx < 4096; idx += 256) {
        const int nn = idx >> 6, cc = idx & 63;
        const long o = ((long)b * NPIX + n0 + nn) * CDIM + c0 + cc;
        tile[nn * 65 + cc] = x2[o] + mlp[o];
    }
    __syncthreads();
    float* op = out + ((long)b * CDIM + c0) * NPIX + n0;
    for (int idx = t; idx < 4096; idx += 256) {
        const int cc = idx >> 6, nn = idx & 63;
        op[(long)cc * NPIX + nn] = tile[nn * 65 + cc];
    }
}

// ---------------------------------------------------------------------------
// Prep kernels
// ---------------------------------------------------------------------------
__global__ void prep_bn_k(const float* __restrict__ w1, const float* __restrict__ b1,
                          const float* __restrict__ m1, const float* __restrict__ v1,
                          const float* __restrict__ w2, const float* __restrict__ b2,
                          const float* __restrict__ m2, const float* __restrict__ v2,
                          const float* __restrict__ db,
                          float* s1, float* t1, float* s2, float* t2)
{
    const int i = threadIdx.x;
    if (i < CDIM) {
        const float a = w1[i] * rsqrtf(v1[i] + BN_EPS);
        s1[i] = a; t1[i] = b1[i] - m1[i] * a;
        const float c = w2[i] * rsqrtf(v2[i] + BN_EPS);
        s2[i] = c; t2[i] = b2[i] - m2[i] * c + db[i] * c;
    }
}

__global__ __launch_bounds__(64) void prep_w_k(
    const float* __restrict__ cw1, const float* __restrict__ cb1,
    const float* __restrict__ cw2, const float* __restrict__ cb2,
    const float* __restrict__ s1, const float* __restrict__ t1,
    const float* __restrict__ s2, const float* __restrict__ t2,
    u16* __restrict__ w1e, float* __restrict__ b1e,
    u16* __restrict__ w2e, float* __restrict__ b2e)
{
    const int o = blockIdx.x;
    const bool sec = (o >= CDIM);
    const int oo = sec ? o - CDIM : o;
    const float* cw = sec ? cw2 : cw1;
    const float* cb = sec ? cb2 : cb1;
    const float* s  = sec ? s2  : s1;
    const float* tt = sec ? t2  : t1;
    u16* we = sec ? w2e : w1e;
    float* be = sec ? b2e : b1e;
    float part = 0.f;
    for (int i = threadIdx.x; i < CDIM; i += 64) {
        const float wv = cw[oo * CDIM + i];
        we[oo * CDIM + i] = f2bf(wv * s[i]);
        part += wv * tt[i];
    }
    for (int off = 32; off; off >>= 1) part += __shfl_down(part, off);
    if (threadIdx.x == 0) be[oo] = cb[oo] + part;
}

__global__ void cvt_k(const float* __restrict__ in, u16* __restrict__ out, int n)
{
    const int i = blockIdx.x * 256 + threadIdx.x;
    if (i < n) out[i] = f2bf(in[i]);
}

__global__ __launch_bounds__(256) void transcvt_k(const float* __restrict__ in,
                                                  u16* __restrict__ out, int R, int C)
{
    __shared__ float tile[64 * 65];
    const int c0 = blockIdx.x << 6, r0 = blockIdx.y << 6;
    const int t = threadIdx.x;
    for (int idx = t; idx < 4096; idx += 256) {
        const int rr = idx >> 6, cc = idx & 63;
        tile[rr * 65 + cc] = in[(long)(r0 + rr) * C + c0 + cc];
    }
    __syncthreads();
    for (int idx = t; idx < 4096; idx += 256) {
        const int cc = idx >> 6, rr = idx & 63;
        out[(long)(c0 + cc) * R + r0 + rr] = f2bf(tile[rr * 65 + cc]);
    }
}

__global__ void dwt_k(const float* __restrict__ dw, u16* __restrict__ o)
{
    const int i = blockIdx.x * 256 + threadIdx.x;
    if (i < 9 * CDIM) {
        const int c = i / 9, tap = i % 9;
        o[tap * CDIM + c] = f2bf(dw[i]);
    }
}

// ---------------------------------------------------------------------------
// Launch
// ---------------------------------------------------------------------------
extern "C" void kernel_launch(void* const* d_in, const int* in_sizes, int n_in,
                              void* d_out, int out_size, void* d_ws, size_t ws_size,
                              hipStream_t stream)
{
    const float* x      = (const float*)d_in[0];
    const float* bn1_w  = (const float*)d_in[1];
    const float* bn1_b  = (const float*)d_in[2];
    const float* bn1_m  = (const float*)d_in[3];
    const float* bn1_v  = (const float*)d_in[4];
    const float* cw1    = (const float*)d_in[5];
    const float* cb1    = (const float*)d_in[6];
    const float* dwW    = (const float*)d_in[7];
    const float* db     = (const float*)d_in[8];
    const float* bn2_w  = (const float*)d_in[9];
    const float* bn2_b  = (const float*)d_in[10];
    const float* bn2_m  = (const float*)d_in[11];
    const float* bn2_v  = (const float*)d_in[12];
    const float* cw2    = (const float*)d_in[13];
    const float* cb2    = (const float*)d_in[14];
    const float* qkv_w  = (const float*)d_in[15];
    const float* proj_w = (const float*)d_in[16];
    const float* proj_b = (const float*)d_in[17];
    const float* ln_w   = (const float*)d_in[18];
    const float* ln_b   = (const float*)d_in[19];
    const float* mlp_w1 = (const float*)d_in[20];
    const float* mlp_b1 = (const float*)d_in[21];
    const float* mlp_w2 = (const float*)d_in[22];
    const float* mlp_b2 = (const float*)d_in[23];
    float* outF = (float*)d_out;

    const long S = (long)NROW * CDIM;   // 9,633,792
    float* wsf = (float*)d_ws;

    // fp32 slots (time-aliased) — identical map to Round 2/3 (proven)
    float* xh_f  = wsf;                       // F0: NHWC x (dead after g2)
    float* x2_f  = wsf;                       // F0: x2 (born g4)
    u16*   v_bf  = (u16*)wsf;                 // F0 during attention (v)
    float* x1_f  = wsf + S;                   // F1: x1 (dead after g4)
    u16*   hmid  = (u16*)(wsf + S);           // F1: mlp hidden half
    u16* ar   = (u16*)(wsf + 2 * S);
    u16* a0   = ar;                           // xh_bf -> x1_bf -> attn_bf -> xn_bf
    u16* a1   = ar + S;                       // h_bf -> qk_bf (spans a1..a2)
    u16* a2   = ar + 2 * S;                   // d_bf
    float* mlp_f = (float*)(ar + S);          // mlp out f32
    u16* wtb   = (u16*)(wsf + 3 * S + S / 2);
    u16* w1e   = wtb;
    u16* w2e   = w1e + CDIM * CDIM;
    u16* qkvw  = w2e + CDIM * CDIM;
    u16* projw = qkvw + 1152 * CDIM;
    u16* mw1t  = projw + CDIM * CDIM;
    u16* mw2t  = mw1t + CMID * CDIM;
    u16* dwt   = mw2t + CDIM * CMID;
    float* fb  = (float*)(dwt + 9 * CDIM);
    float* b1e = fb;
    float* b2e = b1e + CDIM;
    float* s1  = b2e + CDIM;
    float* t1  = s1 + CDIM;
    float* s2  = t1 + CDIM;
    float* t2  = s2 + CDIM;
    float* kvb = t2 + CDIM;
    float* ksb = kvb + 64 * HDIM * HDIM;

    // --- weight prep ---
    prep_bn_k<<<1, CDIM, 0, stream>>>(bn1_w, bn1_b, bn1_m, bn1_v,
                                      bn2_w, bn2_b, bn2_m, bn2_v, db, s1, t1, s2, t2);
    prep_w_k<<<2 * CDIM, 64, 0, stream>>>(cw1, cb1, cw2, cb2, s1, t1, s2, t2,
                                          w1e, b1e, w2e, b2e);
    cvt_k<<<(1152 * CDIM + 255) / 256, 256, 0, stream>>>(qkv_w, qkvw, 1152 * CDIM);
    cvt_k<<<(CDIM * CDIM + 255) / 256, 256, 0, stream>>>(proj_w, projw, CDIM * CDIM);
    transcvt_k<<<dim3(CMID / 64, CDIM / 64), 256, 0, stream>>>(mlp_w1, mw1t, CDIM, CMID);
    transcvt_k<<<dim3(CDIM / 64, CMID / 64), 256, 0, stream>>>(mlp_w2, mw2t, CMID, CDIM);
    dwt_k<<<(9 * CDIM + 255) / 256, 256, 0, stream>>>(dwW, dwt);

    // --- pipeline (all NHWC) ---
    nchw_to_nhwc<<<dim3(49, 6, 8), 256, 0, stream>>>(x, xh_f, a0);
    // g1: h = conv1(x)   (bf16 out, staged)
    gemm_mfma<0, true, false, true, false, 64, false><<<dim3(6, 196), 256, 0, stream>>>(
        a0, w1e, a1, nullptr, nullptr, nullptr, b1e, CDIM, CDIM);
    dwconv_nhwc<<<(int)((long)BB * NPIX * 48 / 256), 256, 0, stream>>>(a1, dwt, a2);
    // g2: x1 = conv2(d) + x   (bf16 staged + f32 direct)
    gemm_mfma<0, true, true, true, true, 64, false><<<dim3(6, 196), 256, 0, stream>>>(
        a2, w2e, a0, nullptr, x1_f, xh_f, b2e, CDIM, CDIM);
    // g3: fused qkv — q|k phi -> a1 (ld 768), v -> v_bf (ld 384)
    gemm_mfma<0, false, false, true, false, 128, true><<<dim3(9, 196), 256, 0, stream>>>(
        a0, qkvw, a1, v_bf, nullptr, nullptr, nullptr, 1152, CDIM);
    // attention
    hipMemsetAsync(kvb, 0, (size_t)(64 * HDIM * HDIM + 64 * HDIM) * sizeof(float), stream);
    attn_kv_k<<<dim3(8, 64), 256, 0, stream>>>(a1, v_bf, kvb, ksb);
    attn_out_k<<<dim3(49, 64), 256, 0, stream>>>(a1, kvb, ksb, a0);
    // g4: x2 = proj(attn) + x1  (f32 only, direct)
    gemm_mfma<0, true, true, false, true, 64, false><<<dim3(6, 196), 256, 0, stream>>>(
        a0, projw, nullptr, nullptr, x2_f, x1_f, proj_b, CDIM, CDIM);
    // LN -> xn (bf16)
    ln_k<<<NROW / 4, 256, 0, stream>>>(x2_f, ln_w, ln_b, a0);
    // MLP in two M-halves
    const long RH = (long)NROW / 2;   // 12544
    gemm_mfma<2, true, false, true, false, 128, false><<<dim3(12, 98), 256, 0, stream>>>(
        a0, mw1t, hmid, nullptr, nullptr, nullptr, mlp_b1, CMID, CDIM);
    gemm_mfma<0, true, false, false, true, 64, false><<<dim3(6, 98), 256, 0, stream>>>(
        hmid, mw2t, nullptr, nullptr, mlp_f, nullptr, mlp_b2, CDIM, CMID);
    gemm_mfma<2, true, false, true, false, 128, false><<<dim3(12, 98), 256, 0, stream>>>(
        a0 + RH * CDIM, mw1t, hmid, nullptr, nullptr, nullptr, mlp_b1, CMID, CDIM);
    gemm_mfma<0, true, false, false, true, 64, false><<<dim3(6, 98), 256, 0, stream>>>(
        hmid, mw2t, nullptr, nullptr, mlp_f + RH * CDIM, nullptr, mlp_b2, CDIM, CMID);
    // final: d_out = NCHW(x2 + mlp)
    final_out<<<dim3(49, 6, 8), 256, 0, stream>>>(x2_f, mlp_f, outF);
}

// Round 5
// 623.492 us; speedup vs baseline: 1.1599x; 1.1015x over previous
//
#include <hip/hip_runtime.h>

#define CDIM 384
#define NPIX 3136          // 56*56
#define BB 8
#define NROW (BB * NPIX)   // 25088
#define HDIM 48
#define CMID 1536
#define BN_EPS 1e-5f
#define LN_EPS 1e-5f

typedef short s16x8 __attribute__((ext_vector_type(8)));
typedef float f32x4 __attribute__((ext_vector_type(4)));
typedef unsigned short u16;

__device__ __forceinline__ u16 f2bf(float f) {
    unsigned u = __builtin_bit_cast(unsigned, f);
    u = (u + 0x7FFFu + ((u >> 16) & 1u)) >> 16;
    return (u16)u;
}
__device__ __forceinline__ float bf2f(u16 h) {
    unsigned u = ((unsigned)h) << 16;
    return __builtin_bit_cast(float, u);
}
__device__ __forceinline__ float phi_act(float v) { return expf(0.5f * (2.f * v - v * v)); }
__device__ __forceinline__ float gelu_act(float v) { return 0.5f * v * (1.f + erff(v * 0.7071067811865476f)); }

#define GLL16(g, l) __builtin_amdgcn_global_load_lds( \
    (const __attribute__((address_space(1))) void*)(g), \
    (__attribute__((address_space(3))) void*)(l), 16, 0, 0)

// ---------------------------------------------------------------------------
// bf16 MFMA GEMM (unchanged from R4): C = act(A * Bw^T + bias) [+ res]
// 128 x TN tile, BK=32, dbuf k-loop, LDS-staged bf16 epilogue (coalesced).
// ---------------------------------------------------------------------------
template<int ACT, bool BIAS, bool RES, bool OBF, bool OF32, int TN, bool QKV>
__global__ __launch_bounds__(256) void gemm_mfma(
    const u16* __restrict__ A, const u16* __restrict__ Bw,
    u16* __restrict__ Cbf, u16* __restrict__ Cv, float* __restrict__ Cf,
    const float* __restrict__ res, const float* __restrict__ bias,
    int N, int K)
{
    constexpr int NFR = TN / 32;
    constexpr int TNw = TN / 2;
    constexpr int STR = TNw + 4;
    constexpr int KLOOP_U16 = 8192 + TN * 64;
    constexpr int STG_U16 = 4 * 64 * STR;
    constexpr int SMEM_N = KLOOP_U16 > STG_U16 ? KLOOP_U16 : STG_U16;
    __shared__ __align__(16) u16 smem[SMEM_N];
    u16* Asb = smem;
    u16* Bsb = smem + 8192;

    const int t  = threadIdx.x;
    const int wv = t >> 6, ln = t & 63;
    const int lm = ln & 15, lq = ln >> 4;
    const int wm = wv >> 1, wn = wv & 1;
    const int m0 = blockIdx.y << 7, n0 = blockIdx.x * TN;

    const u16* gA0 = A  + (long)(m0 + wv * 16 + lm) * K + lq * 8;
    const u16* gA1 = gA0 + (long)64 * K;
    const u16* gB0 = Bw + (long)(n0 + wv * 16 + lm) * K + lq * 8;
    const u16* gB1 = gB0 + (long)64 * K;

    f32x4 acc[4][NFR] = {};
    const int nk = K >> 5;

    GLL16(gA0, &Asb[wv * 512]);
    GLL16(gA1, &Asb[wv * 512 + 2048]);
    GLL16(gB0, &Bsb[wv * 512]);
    if constexpr (TN == 128) GLL16(gB1, &Bsb[wv * 512 + 2048]);

    for (int k = 0; k < nk; k++) {
        const int cur = k & 1;
        __syncthreads();
        if (k + 1 < nk) {
            const int nx = cur ^ 1;
            gA0 += 32; gA1 += 32; gB0 += 32;
            GLL16(gA0, &Asb[nx * 4096 + wv * 512]);
            GLL16(gA1, &Asb[nx * 4096 + wv * 512 + 2048]);
            GLL16(gB0, &Bsb[nx * TN * 32 + wv * 512]);
            if constexpr (TN == 128) { gB1 += 32; GLL16(gB1, &Bsb[nx * TN * 32 + wv * 512 + 2048]); }
        }
        s16x8 av[4], bv[NFR];
        #pragma unroll
        for (int mf = 0; mf < 4; mf++)
            av[mf] = *(const s16x8*)&Asb[cur * 4096 + (wm * 256 + mf * 64 + ln) * 8];
        #pragma unroll
        for (int nf = 0; nf < NFR; nf++)
            bv[nf] = *(const s16x8*)&Bsb[cur * TN * 32 + ((TN == 128 ? wn * 256 : wn * 128) + nf * 64 + ln) * 8];
        #pragma unroll
        for (int mf = 0; mf < 4; mf++)
            #pragma unroll
            for (int nf = 0; nf < NFR; nf++)
                acc[mf][nf] = __builtin_amdgcn_mfma_f32_16x16x32_bf16(
                    av[mf], bv[nf], acc[mf][nf], 0, 0, 0);
    }

    u16* obase = Cbf; int oldc = N; int ocol0 = n0;
    bool qk_phi = false;
    if constexpr (QKV) {
        if (n0 < 768) { obase = Cbf; oldc = 768; ocol0 = n0; qk_phi = true; }
        else          { obase = Cv;  oldc = 384; ocol0 = n0 - 768; }
    }

    if constexpr (OBF || QKV) {
        __syncthreads();
        u16* stg = smem + wv * (64 * STR);
        #pragma unroll
        for (int nf = 0; nf < NFR; nf++) {
            const int lc = nf * 16 + lm;
            const int gn = n0 + wn * TNw + lc;
            const float bval = BIAS ? bias[gn] : 0.f;
            #pragma unroll
            for (int mf = 0; mf < 4; mf++) {
                #pragma unroll
                for (int r = 0; r < 4; r++) {
                    const int lr = mf * 16 + lq * 4 + r;
                    float v = acc[mf][nf][r];
                    if (BIAS) v += bval;
                    if (ACT == 1) v = phi_act(v);
                    else if (ACT == 2) v = gelu_act(v);
                    if (QKV) { if (qk_phi) v = phi_act(v); }
                    const long off = (long)(m0 + wm * 64 + lr) * N + gn;
                    if (RES) v += res[off];
                    if (OF32) Cf[off] = v;
                    stg[lr * STR + lc] = f2bf(v);
                }
            }
        }
        __syncthreads();
        constexpr int CPR = TNw / 8;
        constexpr int RPI = 64 / CPR;
        const int cg = ln % CPR, rb = ln / CPR;
        #pragma unroll
        for (int it = 0; it < 64 / RPI; it++) {
            const int row = it * RPI + rb;
            const s16x8 vv = *(const s16x8*)&stg[row * STR + cg * 8];
            *(s16x8*)&obase[(long)(m0 + wm * 64 + row) * oldc + ocol0 + wn * TNw + cg * 8] = vv;
        }
    } else {
        #pragma unroll
        for (int nf = 0; nf < NFR; nf++) {
            const int gn = n0 + wn * TNw + nf * 16 + lm;
            const float bval = BIAS ? bias[gn] : 0.f;
            #pragma unroll
            for (int mf = 0; mf < 4; mf++) {
                const int gmb = m0 + wm * 64 + mf * 16 + lq * 4;
                #pragma unroll
                for (int r = 0; r < 4; r++) {
                    float v = acc[mf][nf][r];
                    if (BIAS) v += bval;
                    if (ACT == 1) v = phi_act(v);
                    else if (ACT == 2) v = gelu_act(v);
                    const long off = (long)(gmb + r) * N + gn;
                    if (RES) v += res[off];
                    Cf[off] = v;
                }
            }
        }
    }
}

// ---------------------------------------------------------------------------
// NCHW f32 -> NHWC f32 + bf16
// ---------------------------------------------------------------------------
__global__ __launch_bounds__(256) void nchw_to_nhwc(const float* __restrict__ x,
                                                    float* __restrict__ of,
                                                    u16* __restrict__ ob)
{
    __shared__ float tile[64 * 65];
    const int n0 = blockIdx.x << 6, c0 = blockIdx.y << 6, b = blockIdx.z;
    const int t = threadIdx.x;
    const float* ip = x + ((long)b * CDIM + c0) * NPIX + n0;
    for (int idx = t; idx < 4096; idx += 256) {
        const int cc = idx >> 6, nn = idx & 63;
        tile[cc * 65 + nn] = ip[(long)cc * NPIX + nn];
    }
    __syncthreads();
    for (int idx = t; idx < 4096; idx += 256) {
        const int nn = idx >> 6, cc = idx & 63;
        const float v = tile[cc * 65 + nn];
        const long o = ((long)b * NPIX + n0 + nn) * CDIM + c0 + cc;
        of[o] = v; ob[o] = f2bf(v);
    }
}

// ---------------------------------------------------------------------------
// Depthwise 3x3 SAME, NHWC bf16.
// ---------------------------------------------------------------------------
__global__ __launch_bounds__(256) void dwconv_nhwc(const u16* __restrict__ in,
                                                   const u16* __restrict__ wt,
                                                   u16* __restrict__ out)
{
    const long tid = (long)blockIdx.x * 256 + threadIdx.x;
    const int c8 = (int)(tid % 48);
    const int p  = (int)((tid / 48) % NPIX);
    const int b  = (int)(tid / (48LL * NPIX));
    const int y = p / 56, x = p % 56;
    const u16* base = in + (long)b * NPIX * CDIM + c8 * 8;
    float acc[8] = {};
    #pragma unroll
    for (int r = 0; r < 3; r++) {
        const int yy = y + r - 1;
        if ((unsigned)yy >= 56u) continue;
        #pragma unroll
        for (int s = 0; s < 3; s++) {
            const int xx = x + s - 1;
            if ((unsigned)xx >= 56u) continue;
            const s16x8 iv = *(const s16x8*)&base[(long)(yy * 56 + xx) * CDIM];
            const s16x8 wv = *(const s16x8*)&wt[(r * 3 + s) * CDIM + c8 * 8];
            #pragma unroll
            for (int j = 0; j < 8; j++)
                acc[j] = fmaf(bf2f((u16)iv[j]), bf2f((u16)wv[j]), acc[j]);
        }
    }
    s16x8 ov;
    #pragma unroll
    for (int j = 0; j < 8; j++) ov[j] = (short)f2bf(acc[j]);
    *(s16x8*)&out[((long)b * NPIX + p) * CDIM + c8 * 8] = ov;
}

// ---------------------------------------------------------------------------
// MFMA attn stage 1: kv[bh] = K^T V (48x48), ksum[bh][d] = sum_n K[n][d].
// grid (8 splits, 64 bh), 4 waves: staging transposes 64-pixel tiles of k,v
// into LDS [d][n] (stride 72, n-contiguous), waves 0-2 own d-frags 0-2 of kv,
// wave 3 computes ksum via MFMA against splat-1.0. Atomic finish.
// ---------------------------------------------------------------------------
__global__ __launch_bounds__(256) void attn_kv_m(const u16* __restrict__ qk,
                                                 const u16* __restrict__ vb,
                                                 float* __restrict__ kv,
                                                 float* __restrict__ ksum)
{
    const int sp = blockIdx.x, bh = blockIdx.y;
    const int b = bh >> 3, h = bh & 7;
    const u16* kbase = qk + (long)b * NPIX * 768 + 384 + h * HDIM;
    const u16* vbase = vb + (long)b * NPIX * CDIM + h * HDIM;
    __shared__ u16 kt[48 * 72];
    __shared__ u16 vt[48 * 72];
    const int t = threadIdx.x;
    const int wv = t >> 6, ln = t & 63, lm = ln & 15, lq = ln >> 4;

    f32x4 acc[3] = {};
    const s16x8 ones = {0x3F80, 0x3F80, 0x3F80, 0x3F80, 0x3F80, 0x3F80, 0x3F80, 0x3F80};

    for (int tl = sp; tl < 49; tl += 8) {
        const int nn0 = tl << 6;
        __syncthreads();
        for (int idx = t; idx < 384; idx += 256) {
            const int oct = idx >> 6, nn = idx & 63;
            const s16x8 kvv = *(const s16x8*)&kbase[(long)(nn0 + nn) * 768 + oct * 8];
            const s16x8 vvv = *(const s16x8*)&vbase[(long)(nn0 + nn) * CDIM + oct * 8];
            #pragma unroll
            for (int j = 0; j < 8; j++) {
                kt[(oct * 8 + j) * 72 + nn] = (u16)kvv[j];
                vt[(oct * 8 + j) * 72 + nn] = (u16)vvv[j];
            }
        }
        __syncthreads();
        #pragma unroll
        for (int s = 0; s < 2; s++) {
            if (wv < 3) {
                const s16x8 av = *(const s16x8*)&kt[(wv * 16 + lm) * 72 + s * 32 + lq * 8];
                #pragma unroll
                for (int ef = 0; ef < 3; ef++) {
                    const s16x8 bv = *(const s16x8*)&vt[(ef * 16 + lm) * 72 + s * 32 + lq * 8];
                    acc[ef] = __builtin_amdgcn_mfma_f32_16x16x32_bf16(av, bv, acc[ef], 0, 0, 0);
                }
            } else {
                #pragma unroll
                for (int mf = 0; mf < 3; mf++) {
                    const s16x8 av = *(const s16x8*)&kt[(mf * 16 + lm) * 72 + s * 32 + lq * 8];
                    acc[mf] = __builtin_amdgcn_mfma_f32_16x16x32_bf16(av, ones, acc[mf], 0, 0, 0);
                }
            }
        }
    }
    if (wv < 3) {
        // D layout: col(e) = lane&15, row(d) = (lane>>4)*4 + r
        #pragma unroll
        for (int ef = 0; ef < 3; ef++)
            #pragma unroll
            for (int r = 0; r < 4; r++)
                atomicAdd(&kv[(long)bh * 2304 + (wv * 16 + lq * 4 + r) * 48 + ef * 16 + lm], acc[ef][r]);
    } else {
        if (lm == 0) {
            #pragma unroll
            for (int mf = 0; mf < 3; mf++)
                #pragma unroll
                for (int r = 0; r < 4; r++)
                    atomicAdd(&ksum[bh * 48 + mf * 16 + lq * 4 + r], acc[mf][r]);
        }
    }
}

// kv f32 -> kv_pad bf16 [bh][e][64] (cols d, d>=48 zero); ksum -> [bh][64]
__global__ void repack_kv(const float* __restrict__ kvb, const float* __restrict__ ksb,
                          u16* __restrict__ kvp, u16* __restrict__ ksp)
{
    const int bh = blockIdx.x, t = threadIdx.x;
    for (int idx = t; idx < 3072; idx += 256) {
        const int e = idx >> 6, d = idx & 63;
        kvp[(long)bh * 3072 + idx] = (d < 48) ? f2bf(kvb[(long)bh * 2304 + d * 48 + e]) : (u16)0;
    }
    if (t < 64) ksp[bh * 64 + t] = (t < 48) ? f2bf(ksb[bh * 48 + t]) : (u16)0;
}

// ---------------------------------------------------------------------------
// MFMA attn stage 2: out[n][h*48+e] = (Q kv)[n][e] / (Q.ksum + eps).
// grid (49 m-tiles, 2 h-groups, 8 b); wave = head. Private GLL staging of
// Q 64x64 (K-pad into next head's cols x zero kv rows) and kv_pad 48x64;
// normalizer via 4th MFMA column against ksum frag. Group-coalesced output.
// ---------------------------------------------------------------------------
__global__ __launch_bounds__(256) void attn_out_m(const u16* __restrict__ qk,
                                                  const u16* __restrict__ kvp,
                                                  const u16* __restrict__ ksp,
                                                  u16* __restrict__ outb)
{
    __shared__ __align__(16) u16 smem[4 * 7168];   // per wave: A 4096 + B 3072
    const int mt = blockIdx.x, hh = blockIdx.y, b = blockIdx.z;
    const int t = threadIdx.x, wv = t >> 6, ln = t & 63, lm = ln & 15, lq = ln >> 4;
    const int h = hh * 4 + wv, bh = b * 8 + h;
    u16* As = smem + wv * 7168;
    u16* Bs = As + 4096;
    const u16* Ab = qk + ((long)b * NPIX + mt * 64) * 768 + h * HDIM;
    const u16* Bb = kvp + (long)bh * 3072;

    #pragma unroll
    for (int rg = 0; rg < 4; rg++)
        #pragma unroll
        for (int oh = 0; oh < 2; oh++)
            GLL16(Ab + (long)(rg * 16 + lm) * 768 + oh * 32 + lq * 8, As + (rg * 128 + oh * 64) * 8);
    #pragma unroll
    for (int rg = 0; rg < 3; rg++)
        #pragma unroll
        for (int oh = 0; oh < 2; oh++)
            GLL16(Bb + (rg * 16 + lm) * 64 + oh * 32 + lq * 8, Bs + (rg * 128 + oh * 64) * 8);

    s16x8 kz[2];
    kz[0] = *(const s16x8*)&ksp[bh * 64 + lq * 8];
    kz[1] = *(const s16x8*)&ksp[bh * 64 + 32 + lq * 8];

    __syncthreads();   // drain GLLs

    f32x4 acc[4][3] = {};
    f32x4 accz[4] = {};
    #pragma unroll
    for (int s = 0; s < 2; s++) {
        s16x8 av[4], bv[3];
        #pragma unroll
        for (int mf = 0; mf < 4; mf++)
            av[mf] = *(const s16x8*)&As[(mf * 128 + s * 64 + ln) * 8];
        #pragma unroll
        for (int nf = 0; nf < 3; nf++)
            bv[nf] = *(const s16x8*)&Bs[(nf * 128 + s * 64 + ln) * 8];
        #pragma unroll
        for (int mf = 0; mf < 4; mf++) {
            #pragma unroll
            for (int nf = 0; nf < 3; nf++)
                acc[mf][nf] = __builtin_amdgcn_mfma_f32_16x16x32_bf16(av[mf], bv[nf], acc[mf][nf], 0, 0, 0);
            accz[mf] = __builtin_amdgcn_mfma_f32_16x16x32_bf16(av[mf], kz[s], accz[mf], 0, 0, 0);
        }
    }

    // stage out tile 64 rows x 48 e (stride 56) in A region
    u16* stg = As;
    #pragma unroll
    for (int mf = 0; mf < 4; mf++) {
        #pragma unroll
        for (int r = 0; r < 4; r++) {
            const float z = 1.f / (accz[mf][r] + 1e-6f);
            const int row = mf * 16 + lq * 4 + r;
            #pragma unroll
            for (int nf = 0; nf < 3; nf++)
                stg[row * 56 + nf * 16 + lm] = f2bf(acc[mf][nf][r] * z);
        }
    }
    __syncthreads();

    // cooperative write: 64 rows x 192 cols (4 heads), 384B contiguous per row
    #pragma unroll
    for (int it = 0; it < 6; it++) {
        const int idx = it * 256 + t;        // 0..1535
        const int row = idx / 24, c = idx % 24;
        const int sw = c / 6, c6 = c % 6;
        const s16x8 vvv = *(const s16x8*)&smem[sw * 7168 + row * 56 + c6 * 8];
        *(s16x8*)&outb[((long)b * NPIX + mt * 64 + row) * CDIM + hh * 192 + c * 8] = vvv;
    }
}

// ---------------------------------------------------------------------------
// LayerNorm over contiguous 384 channels (NHWC)
// ---------------------------------------------------------------------------
__global__ __launch_bounds__(256) void ln_k(const float* __restrict__ x2,
                                            const float* __restrict__ lw,
                                            const float* __restrict__ lb,
                                            u16* __restrict__ xn)
{
    const int row = blockIdx.x * 4 + (threadIdx.x >> 6);
    const int lane = threadIdx.x & 63;
    const float* rp = x2 + (long)row * CDIM;
    float2 v[3];
    float sum = 0.f, sq = 0.f;
    #pragma unroll
    for (int i = 0; i < 3; i++) {
        v[i] = *(const float2*)&rp[lane * 2 + i * 128];
        sum += v[i].x + v[i].y;
        sq = fmaf(v[i].x, v[i].x, fmaf(v[i].y, v[i].y, sq));
    }
    #pragma unroll
    for (int off = 1; off < 64; off <<= 1) {
        sum += __shfl_xor(sum, off);
        sq  += __shfl_xor(sq, off);
    }
    const float mu = sum * (1.f / CDIM);
    const float rs = rsqrtf(sq * (1.f / CDIM) - mu * mu + LN_EPS);
    u16* op = xn + (long)row * CDIM;
    #pragma unroll
    for (int i = 0; i < 3; i++) {
        const int c = lane * 2 + i * 128;
        op[c]     = f2bf((v[i].x - mu) * rs * lw[c] + lb[c]);
        op[c + 1] = f2bf((v[i].y - mu) * rs * lw[c + 1] + lb[c + 1]);
    }
}

// ---------------------------------------------------------------------------
// d_out NCHW = transpose(x2 + mlp) from NHWC f32
// ---------------------------------------------------------------------------
__global__ __launch_bounds__(256) void final_out(const float* __restrict__ x2,
                                                 const float* __restrict__ mlp,
                                                 float* __restrict__ out)
{
    __shared__ float tile[64 * 65];
    const int n0 = blockIdx.x << 6, c0 = blockIdx.y << 6, b = blockIdx.z;
    const int t = threadIdx.x;
    for (int idx = t; idx < 4096; idx += 256) {
        const int nn = idx >> 6, cc = idx & 63;
        const long o = ((long)b * NPIX + n0 + nn) * CDIM + c0 + cc;
        tile[nn * 65 + cc] = x2[o] + mlp[o];
    }
    __syncthreads();
    float* op = out + ((long)b * CDIM + c0) * NPIX + n0;
    for (int idx = t; idx < 4096; idx += 256) {
        const int cc = idx >> 6, nn = idx & 63;
        op[(long)cc * NPIX + nn] = tile[nn * 65 + cc];
    }
}

// ---------------------------------------------------------------------------
// Prep kernels
// ---------------------------------------------------------------------------
__global__ void prep_bn_k(const float* __restrict__ w1, const float* __restrict__ b1,
                          const float* __restrict__ m1, const float* __restrict__ v1,
                          const float* __restrict__ w2, const float* __restrict__ b2,
                          const float* __restrict__ m2, const float* __restrict__ v2,
                          const float* __restrict__ db,
                          float* s1, float* t1, float* s2, float* t2)
{
    const int i = threadIdx.x;
    if (i < CDIM) {
        const float a = w1[i] * rsqrtf(v1[i] + BN_EPS);
        s1[i] = a; t1[i] = b1[i] - m1[i] * a;
        const float c = w2[i] * rsqrtf(v2[i] + BN_EPS);
        s2[i] = c; t2[i] = b2[i] - m2[i] * c + db[i] * c;
    }
}

__global__ __launch_bounds__(64) void prep_w_k(
    const float* __restrict__ cw1, const float* __restrict__ cb1,
    const float* __restrict__ cw2, const float* __restrict__ cb2,
    const float* __restrict__ s1, const float* __restrict__ t1,
    const float* __restrict__ s2, const float* __restrict__ t2,
    u16* __restrict__ w1e, float* __restrict__ b1e,
    u16* __restrict__ w2e, float* __restrict__ b2e)
{
    const int o = blockIdx.x;
    const bool sec = (o >= CDIM);
    const int oo = sec ? o - CDIM : o;
    const float* cw = sec ? cw2 : cw1;
    const float* cb = sec ? cb2 : cb1;
    const float* s  = sec ? s2  : s1;
    const float* tt = sec ? t2  : t1;
    u16* we = sec ? w2e : w1e;
    float* be = sec ? b2e : b1e;
    float part = 0.f;
    for (int i = threadIdx.x; i < CDIM; i += 64) {
        const float wv = cw[oo * CDIM + i];
        we[oo * CDIM + i] = f2bf(wv * s[i]);
        part += wv * tt[i];
    }
    for (int off = 32; off; off >>= 1) part += __shfl_down(part, off);
    if (threadIdx.x == 0) be[oo] = cb[oo] + part;
}

__global__ void cvt_k(const float* __restrict__ in, u16* __restrict__ out, int n)
{
    const int i = blockIdx.x * 256 + threadIdx.x;
    if (i < n) out[i] = f2bf(in[i]);
}

__global__ __launch_bounds__(256) void transcvt_k(const float* __restrict__ in,
                                                  u16* __restrict__ out, int R, int C)
{
    __shared__ float tile[64 * 65];
    const int c0 = blockIdx.x << 6, r0 = blockIdx.y << 6;
    const int t = threadIdx.x;
    for (int idx = t; idx < 4096; idx += 256) {
        const int rr = idx >> 6, cc = idx & 63;
        tile[rr * 65 + cc] = in[(long)(r0 + rr) * C + c0 + cc];
    }
    __syncthreads();
    for (int idx = t; idx < 4096; idx += 256) {
        const int cc = idx >> 6, rr = idx & 63;
        out[(long)(c0 + cc) * R + r0 + rr] = f2bf(tile[rr * 65 + cc]);
    }
}

__global__ void dwt_k(const float* __restrict__ dw, u16* __restrict__ o)
{
    const int i = blockIdx.x * 256 + threadIdx.x;
    if (i < 9 * CDIM) {
        const int c = i / 9, tap = i % 9;
        o[tap * CDIM + c] = f2bf(dw[i]);
    }
}

// ---------------------------------------------------------------------------
// Launch
// ---------------------------------------------------------------------------
extern "C" void kernel_launch(void* const* d_in, const int* in_sizes, int n_in,
                              void* d_out, int out_size, void* d_ws, size_t ws_size,
                              hipStream_t stream)
{
    const float* x      = (const float*)d_in[0];
    const float* bn1_w  = (const float*)d_in[1];
    const float* bn1_b  = (const float*)d_in[2];
    const float* bn1_m  = (const float*)d_in[3];
    const float* bn1_v  = (const float*)d_in[4];
    const float* cw1    = (const float*)d_in[5];
    const float* cb1    = (const float*)d_in[6];
    const float* dwW    = (const float*)d_in[7];
    const float* db     = (const float*)d_in[8];
    const float* bn2_w  = (const float*)d_in[9];
    const float* bn2_b  = (const float*)d_in[10];
    const float* bn2_m  = (const float*)d_in[11];
    const float* bn2_v  = (const float*)d_in[12];
    const float* cw2    = (const float*)d_in[13];
    const float* cb2    = (const float*)d_in[14];
    const float* qkv_w  = (const float*)d_in[15];
    const float* proj_w = (const float*)d_in[16];
    const float* proj_b = (const float*)d_in[17];
    const float* ln_w   = (const float*)d_in[18];
    const float* ln_b   = (const float*)d_in[19];
    const float* mlp_w1 = (const float*)d_in[20];
    const float* mlp_b1 = (const float*)d_in[21];
    const float* mlp_w2 = (const float*)d_in[22];
    const float* mlp_b2 = (const float*)d_in[23];
    float* outF = (float*)d_out;

    const long S = (long)NROW * CDIM;   // 9,633,792
    float* wsf = (float*)d_ws;

    float* xh_f  = wsf;                       // F0: NHWC x (dead after g2)
    float* x2_f  = wsf;                       // F0: x2 (born g4)
    u16*   v_bf  = (u16*)wsf;                 // F0 during attention (v)
    float* x1_f  = wsf + S;                   // F1: x1 (dead after g4)
    u16*   hmid  = (u16*)(wsf + S);           // F1: mlp hidden half
    u16* ar   = (u16*)(wsf + 2 * S);
    u16* a0   = ar;                           // xh_bf -> x1_bf -> attn_bf -> xn_bf
    u16* a1   = ar + S;                       // h_bf -> qk_bf (spans a1..a2)
    u16* a2   = ar + 2 * S;                   // d_bf
    float* mlp_f = (float*)(ar + S);          // mlp out f32
    u16* wtb   = (u16*)(wsf + 3 * S + S / 2);
    u16* w1e   = wtb;
    u16* w2e   = w1e + CDIM * CDIM;
    u16* qkvw  = w2e + CDIM * CDIM;
    u16* projw = qkvw + 1152 * CDIM;
    u16* mw1t  = projw + CDIM * CDIM;
    u16* mw2t  = mw1t + CMID * CDIM;
    u16* dwt   = mw2t + CDIM * CMID;
    float* fb  = (float*)(dwt + 9 * CDIM);
    float* b1e = fb;
    float* b2e = b1e + CDIM;
    float* s1  = b2e + CDIM;
    float* t1  = s1 + CDIM;
    float* s2  = t1 + CDIM;
    float* t2  = s2 + CDIM;
    float* kvb = t2 + CDIM;                   // 64*48*48 f32
    float* ksb = kvb + 64 * HDIM * HDIM;      // 64*48 f32
    u16*   kvp = (u16*)(ksb + 64 * HDIM);     // 64*48*64 bf16 (K-padded, transposed)
    u16*   ksp = kvp + 64 * 3072;             // 64*64 bf16

    // --- weight prep ---
    prep_bn_k<<<1, CDIM, 0, stream>>>(bn1_w, bn1_b, bn1_m, bn1_v,
                                      bn2_w, bn2_b, bn2_m, bn2_v, db, s1, t1, s2, t2);
    prep_w_k<<<2 * CDIM, 64, 0, stream>>>(cw1, cb1, cw2, cb2, s1, t1, s2, t2,
                                          w1e, b1e, w2e, b2e);
    cvt_k<<<(1152 * CDIM + 255) / 256, 256, 0, stream>>>(qkv_w, qkvw, 1152 * CDIM);
    cvt_k<<<(CDIM * CDIM + 255) / 256, 256, 0, stream>>>(proj_w, projw, CDIM * CDIM);
    transcvt_k<<<dim3(CMID / 64, CDIM / 64), 256, 0, stream>>>(mlp_w1, mw1t, CDIM, CMID);
    transcvt_k<<<dim3(CDIM / 64, CMID / 64), 256, 0, stream>>>(mlp_w2, mw2t, CMID, CDIM);
    dwt_k<<<(9 * CDIM + 255) / 256, 256, 0, stream>>>(dwW, dwt);

    // --- pipeline (all NHWC) ---
    nchw_to_nhwc<<<dim3(49, 6, 8), 256, 0, stream>>>(x, xh_f, a0);
    gemm_mfma<0, true, false, true, false, 64, false><<<dim3(6, 196), 256, 0, stream>>>(
        a0, w1e, a1, nullptr, nullptr, nullptr, b1e, CDIM, CDIM);
    dwconv_nhwc<<<(int)((long)BB * NPIX * 48 / 256), 256, 0, stream>>>(a1, dwt, a2);
    gemm_mfma<0, true, true, true, true, 64, false><<<dim3(6, 196), 256, 0, stream>>>(
        a2, w2e, a0, nullptr, x1_f, xh_f, b2e, CDIM, CDIM);
    // fused qkv — q|k phi -> a1 (ld 768), v -> v_bf (ld 384)
    gemm_mfma<0, false, false, true, false, 128, true><<<dim3(9, 196), 256, 0, stream>>>(
        a0, qkvw, a1, v_bf, nullptr, nullptr, nullptr, 1152, CDIM);
    // attention (MFMA)
    hipMemsetAsync(kvb, 0, (size_t)(64 * HDIM * HDIM + 64 * HDIM) * sizeof(float), stream);
    attn_kv_m<<<dim3(8, 64), 256, 0, stream>>>(a1, v_bf, kvb, ksb);
    repack_kv<<<64, 256, 0, stream>>>(kvb, ksb, kvp, ksp);
    attn_out_m<<<dim3(49, 2, 8), 256, 0, stream>>>(a1, kvp, ksp, a0);
    // x2 = proj(attn) + x1  (f32 only, direct)
    gemm_mfma<0, true, true, false, true, 64, false><<<dim3(6, 196), 256, 0, stream>>>(
        a0, projw, nullptr, nullptr, x2_f, x1_f, proj_b, CDIM, CDIM);
    // LN -> xn (bf16)
    ln_k<<<NROW / 4, 256, 0, stream>>>(x2_f, ln_w, ln_b, a0);
    // MLP in two M-halves
    const long RH = (long)NROW / 2;   // 12544
    gemm_mfma<2, true, false, true, false, 128, false><<<dim3(12, 98), 256, 0, stream>>>(
        a0, mw1t, hmid, nullptr, nullptr, nullptr, mlp_b1, CMID, CDIM);
    gemm_mfma<0, true, false, false, true, 64, false><<<dim3(6, 98), 256, 0, stream>>>(
        hmid, mw2t, nullptr, nullptr, mlp_f, nullptr, mlp_b2, CDIM, CMID);
    gemm_mfma<2, true, false, true, false, 128, false><<<dim3(12, 98), 256, 0, stream>>>(
        a0 + RH * CDIM, mw1t, hmid, nullptr, nullptr, nullptr, mlp_b1, CMID, CDIM);
    gemm_mfma<0, true, false, false, true, 64, false><<<dim3(6, 98), 256, 0, stream>>>(
        hmid, mw2t, nullptr, nullptr, mlp_f + RH * CDIM, nullptr, mlp_b2, CDIM, CMID);
    // final: d_out = NCHW(x2 + mlp)
    final_out<<<dim3(49, 6, 8), 256, 0, stream>>>(x2_f, mlp_f, outF);
}

// Round 7
// 566.169 us; speedup vs baseline: 1.2773x; 1.1012x over previous
//
#include <hip/hip_runtime.h>

#define CDIM 384
#define NPIX 3136          // 56*56
#define BB 8
#define NROW (BB * NPIX)   // 25088
#define HDIM 48
#define CMID 1536
#define BN_EPS 1e-5f
#define LN_EPS 1e-5f

typedef short s16x8 __attribute__((ext_vector_type(8)));
typedef float f32x4 __attribute__((ext_vector_type(4)));
typedef unsigned short u16;

__device__ __forceinline__ u16 f2bf(float f) {
    unsigned u = __builtin_bit_cast(unsigned, f);
    u = (u + 0x7FFFu + ((u >> 16) & 1u)) >> 16;
    return (u16)u;
}
__device__ __forceinline__ float bf2f(u16 h) {
    unsigned u = ((unsigned)h) << 16;
    return __builtin_bit_cast(float, u);
}
__device__ __forceinline__ float phi_act(float v) { return expf(0.5f * (2.f * v - v * v)); }
__device__ __forceinline__ float gelu_act(float v) { return 0.5f * v * (1.f + erff(v * 0.7071067811865476f)); }

#define GLL16(g, l) __builtin_amdgcn_global_load_lds( \
    (const __attribute__((address_space(1))) void*)(g), \
    (__attribute__((address_space(3))) void*)(l), 16, 0, 0)

// ---------------------------------------------------------------------------
// bf16 MFMA GEMM: C = act(A * Bw^T + bias) [+ res]
// 128 x TN tile, BK=32, dbuf k-loop, LDS-staged bf16 epilogue.
// XCD-aware block swizzle; RES mode 0/1(f32)/2(bf16); ONCHW epilogue
// (f32 NCHW-transposed output with residual, for mlp2 -> d_out).
// R7 FIX: SMEM_N now includes the ONCHW staging size (64*132 f32 =
// 16896 u16) — R6 overflowed the 24576-B k-loop allocation by ~9 KB.
// ---------------------------------------------------------------------------
template<int ACT, bool BIAS, int RES, bool OBF, bool OF32, bool ONCHW, int TN, bool QKV>
__global__ __launch_bounds__(256) void gemm_mfma(
    const u16* __restrict__ A, const u16* __restrict__ Bw,
    u16* __restrict__ Cbf, u16* __restrict__ Cv, float* __restrict__ Cf,
    const void* __restrict__ resv, const float* __restrict__ bias,
    int N, int K, long mrow0)
{
    constexpr int NFR = TN / 32;
    constexpr int TNw = TN / 2;
    constexpr int STR = TNw + 4;
    constexpr int KLOOP_U16 = 8192 + TN * 64;
    constexpr int STG_U16 = 4 * 64 * STR;
    constexpr int ONCHW_U16 = ONCHW ? (64 * 132 * 2) : 0;   // 64 cols x 132 f32 stride
    constexpr int SMEM_A = KLOOP_U16 > STG_U16 ? KLOOP_U16 : STG_U16;
    constexpr int SMEM_N = SMEM_A > ONCHW_U16 ? SMEM_A : ONCHW_U16;
    __shared__ __align__(16) u16 smem[SMEM_N];
    u16* Asb = smem;
    u16* Bsb = smem + 8192;

    // XCD swizzle: HW assigns flat%8 -> XCD (round-robin). Remap so each XCD
    // processes a contiguous n-fastest chunk => A-tile reuse hits its L2.
    const int total = gridDim.x * gridDim.y;
    const int flat = blockIdx.y * gridDim.x + blockIdx.x;
    const int nx8 = total >> 3, rem = total & 7;
    const int xcd = flat & 7, slot = flat >> 3;
    const int nf2 = xcd * nx8 + (xcd < rem ? xcd : rem) + slot;
    const int by = nf2 / gridDim.x, bx = nf2 - by * gridDim.x;

    const int t  = threadIdx.x;
    const int wv = t >> 6, ln = t & 63;
    const int lm = ln & 15, lq = ln >> 4;
    const int wm = wv >> 1, wn = wv & 1;
    const int m0 = by << 7, n0 = bx * TN;

    const u16* gA0 = A  + (long)(m0 + wv * 16 + lm) * K + lq * 8;
    const u16* gA1 = gA0 + (long)64 * K;
    const u16* gB0 = Bw + (long)(n0 + wv * 16 + lm) * K + lq * 8;
    const u16* gB1 = gB0 + (long)64 * K;

    f32x4 acc[4][NFR] = {};
    const int nk = K >> 5;

    GLL16(gA0, &Asb[wv * 512]);
    GLL16(gA1, &Asb[wv * 512 + 2048]);
    GLL16(gB0, &Bsb[wv * 512]);
    if constexpr (TN == 128) GLL16(gB1, &Bsb[wv * 512 + 2048]);

    for (int k = 0; k < nk; k++) {
        const int cur = k & 1;
        __syncthreads();
        if (k + 1 < nk) {
            const int nx = cur ^ 1;
            gA0 += 32; gA1 += 32; gB0 += 32;
            GLL16(gA0, &Asb[nx * 4096 + wv * 512]);
            GLL16(gA1, &Asb[nx * 4096 + wv * 512 + 2048]);
            GLL16(gB0, &Bsb[nx * TN * 32 + wv * 512]);
            if constexpr (TN == 128) { gB1 += 32; GLL16(gB1, &Bsb[nx * TN * 32 + wv * 512 + 2048]); }
        }
        s16x8 av[4], bv[NFR];
        #pragma unroll
        for (int mf = 0; mf < 4; mf++)
            av[mf] = *(const s16x8*)&Asb[cur * 4096 + (wm * 256 + mf * 64 + ln) * 8];
        #pragma unroll
        for (int nf = 0; nf < NFR; nf++)
            bv[nf] = *(const s16x8*)&Bsb[cur * TN * 32 + ((TN == 128 ? wn * 256 : wn * 128) + nf * 64 + ln) * 8];
        #pragma unroll
        for (int mf = 0; mf < 4; mf++)
            #pragma unroll
            for (int nf = 0; nf < NFR; nf++)
                acc[mf][nf] = __builtin_amdgcn_mfma_f32_16x16x32_bf16(
                    av[mf], bv[nf], acc[mf][nf], 0, 0, 0);
    }

    u16* obase = Cbf; int oldc = N; int ocol0 = n0;
    bool qk_phi = false;
    if constexpr (QKV) {
        if (n0 < 768) { obase = Cbf; oldc = 768; ocol0 = n0; qk_phi = true; }
        else          { obase = Cv;  oldc = 384; ocol0 = n0 - 768; }
    }

    if constexpr (OBF || QKV) {
        __syncthreads();
        u16* stg = smem + wv * (64 * STR);
        #pragma unroll
        for (int nf = 0; nf < NFR; nf++) {
            const int lc = nf * 16 + lm;
            const int gn = n0 + wn * TNw + lc;
            const float bval = BIAS ? bias[gn] : 0.f;
            #pragma unroll
            for (int mf = 0; mf < 4; mf++) {
                #pragma unroll
                for (int r = 0; r < 4; r++) {
                    const int lr = mf * 16 + lq * 4 + r;
                    float v = acc[mf][nf][r];
                    if (BIAS) v += bval;
                    if (ACT == 1) v = phi_act(v);
                    else if (ACT == 2) v = gelu_act(v);
                    if (QKV) { if (qk_phi) v = phi_act(v); }
                    const long off = (long)(m0 + wm * 64 + lr) * N + gn;
                    if (RES == 1) v += ((const float*)resv)[off];
                    else if (RES == 2) v += bf2f(((const u16*)resv)[off]);
                    if (OF32) Cf[off] = v;
                    stg[lr * STR + lc] = f2bf(v);
                }
            }
        }
        __syncthreads();
        constexpr int CPR = TNw / 8;
        constexpr int RPI = 64 / CPR;
        const int cg = ln % CPR, rb = ln / CPR;
        #pragma unroll
        for (int it = 0; it < 64 / RPI; it++) {
            const int row = it * RPI + rb;
            const s16x8 vv = *(const s16x8*)&stg[row * STR + cg * 8];
            *(s16x8*)&obase[(long)(m0 + wm * 64 + row) * oldc + ocol0 + wn * TNw + cg * 8] = vv;
        }
    } else if constexpr (ONCHW) {
        // f32 output, transposed to NCHW, with f32 residual. TN==64 only.
        __syncthreads();
        float* stgf = (float*)smem;          // [col][row], col stride 132 f32
        const float* resf = (const float*)resv;
        #pragma unroll
        for (int nf = 0; nf < NFR; nf++) {
            const int lc = nf * 16 + lm;
            const int col = wn * TNw + lc;
            const int gn = n0 + col;
            const float bval = BIAS ? bias[gn] : 0.f;
            #pragma unroll
            for (int mf = 0; mf < 4; mf++) {
                float4 q;
                float* qq = (float*)&q;
                #pragma unroll
                for (int r = 0; r < 4; r++) {
                    const int lr = mf * 16 + lq * 4 + r;
                    float v = acc[mf][nf][r];
                    if (BIAS) v += bval;
                    if (ACT == 1) v = phi_act(v);
                    else if (ACT == 2) v = gelu_act(v);
                    if (RES == 1) v += resf[(long)(m0 + wm * 64 + lr) * N + gn];
                    qq[r] = v;
                }
                *(float4*)&stgf[col * 132 + wm * 64 + mf * 16 + lq * 4] = q;
            }
        }
        __syncthreads();
        #pragma unroll
        for (int it = 0; it < 8; it++) {
            const int c = it * 8 + (t >> 5);
            const int mloc = (t & 31) * 4;
            const float4 vv = *(const float4*)&stgf[c * 132 + mloc];
            const long mg = mrow0 + m0 + mloc;
            const int b = (int)(mg / NPIX);
            const int n = (int)(mg % NPIX);
            *(float4*)&Cf[((long)b * CDIM + n0 + c) * NPIX + n] = vv;
        }
    } else {
        #pragma unroll
        for (int nf = 0; nf < NFR; nf++) {
            const int gn = n0 + wn * TNw + nf * 16 + lm;
            const float bval = BIAS ? bias[gn] : 0.f;
            #pragma unroll
            for (int mf = 0; mf < 4; mf++) {
                const int gmb = m0 + wm * 64 + mf * 16 + lq * 4;
                #pragma unroll
                for (int r = 0; r < 4; r++) {
                    float v = acc[mf][nf][r];
                    if (BIAS) v += bval;
                    if (ACT == 1) v = phi_act(v);
                    else if (ACT == 2) v = gelu_act(v);
                    const long off = (long)(gmb + r) * N + gn;
                    if (RES == 1) v += ((const float*)resv)[off];
                    else if (RES == 2) v += bf2f(((const u16*)resv)[off]);
                    Cf[off] = v;
                }
            }
        }
    }
}

// ---------------------------------------------------------------------------
// NCHW f32 -> NHWC bf16
// ---------------------------------------------------------------------------
__global__ __launch_bounds__(256) void nchw_to_bf(const float* __restrict__ x,
                                                  u16* __restrict__ ob)
{
    __shared__ float tile[64 * 65];
    const int n0 = blockIdx.x << 6, c0 = blockIdx.y << 6, b = blockIdx.z;
    const int t = threadIdx.x;
    const float* ip = x + ((long)b * CDIM + c0) * NPIX + n0;
    for (int idx = t; idx < 4096; idx += 256) {
        const int cc = idx >> 6, nn = idx & 63;
        tile[cc * 65 + nn] = ip[(long)cc * NPIX + nn];
    }
    __syncthreads();
    for (int idx = t; idx < 4096; idx += 256) {
        const int nn = idx >> 6, cc = idx & 63;
        ob[((long)b * NPIX + n0 + nn) * CDIM + c0 + cc] = f2bf(tile[cc * 65 + nn]);
    }
}

// ---------------------------------------------------------------------------
// Depthwise 3x3 SAME, NHWC bf16.
// ---------------------------------------------------------------------------
__global__ __launch_bounds__(256) void dwconv_nhwc(const u16* __restrict__ in,
                                                   const u16* __restrict__ wt,
                                                   u16* __restrict__ out)
{
    const long tid = (long)blockIdx.x * 256 + threadIdx.x;
    const int c8 = (int)(tid % 48);
    const int p  = (int)((tid / 48) % NPIX);
    const int b  = (int)(tid / (48LL * NPIX));
    const int y = p / 56, x = p % 56;
    const u16* base = in + (long)b * NPIX * CDIM + c8 * 8;
    float acc[8] = {};
    #pragma unroll
    for (int r = 0; r < 3; r++) {
        const int yy = y + r - 1;
        if ((unsigned)yy >= 56u) continue;
        #pragma unroll
        for (int s = 0; s < 3; s++) {
            const int xx = x + s - 1;
            if ((unsigned)xx >= 56u) continue;
            const s16x8 iv = *(const s16x8*)&base[(long)(yy * 56 + xx) * CDIM];
            const s16x8 wv = *(const s16x8*)&wt[(r * 3 + s) * CDIM + c8 * 8];
            #pragma unroll
            for (int j = 0; j < 8; j++)
                acc[j] = fmaf(bf2f((u16)iv[j]), bf2f((u16)wv[j]), acc[j]);
        }
    }
    s16x8 ov;
    #pragma unroll
    for (int j = 0; j < 8; j++) ov[j] = (short)f2bf(acc[j]);
    *(s16x8*)&out[((long)b * NPIX + p) * CDIM + c8 * 8] = ov;
}

// ---------------------------------------------------------------------------
// MFMA attn stage 1: kv[bh] = K^T V (48x48), ksum via MFMA vs splat-1.0.
// ---------------------------------------------------------------------------
__global__ __launch_bounds__(256) void attn_kv_m(const u16* __restrict__ qk,
                                                 const u16* __restrict__ vb,
                                                 float* __restrict__ kv,
                                                 float* __restrict__ ksum)
{
    const int sp = blockIdx.x, bh = blockIdx.y;
    const int b = bh >> 3, h = bh & 7;
    const u16* kbase = qk + (long)b * NPIX * 768 + 384 + h * HDIM;
    const u16* vbase = vb + (long)b * NPIX * CDIM + h * HDIM;
    __shared__ u16 kt[48 * 72];
    __shared__ u16 vt[48 * 72];
    const int t = threadIdx.x;
    const int wv = t >> 6, ln = t & 63, lm = ln & 15, lq = ln >> 4;

    f32x4 acc[3] = {};
    const s16x8 ones = {0x3F80, 0x3F80, 0x3F80, 0x3F80, 0x3F80, 0x3F80, 0x3F80, 0x3F80};

    for (int tl = sp; tl < 49; tl += 8) {
        const int nn0 = tl << 6;
        __syncthreads();
        for (int idx = t; idx < 384; idx += 256) {
            const int oct = idx >> 6, nn = idx & 63;
            const s16x8 kvv = *(const s16x8*)&kbase[(long)(nn0 + nn) * 768 + oct * 8];
            const s16x8 vvv = *(const s16x8*)&vbase[(long)(nn0 + nn) * CDIM + oct * 8];
            #pragma unroll
            for (int j = 0; j < 8; j++) {
                kt[(oct * 8 + j) * 72 + nn] = (u16)kvv[j];
                vt[(oct * 8 + j) * 72 + nn] = (u16)vvv[j];
            }
        }
        __syncthreads();
        #pragma unroll
        for (int s = 0; s < 2; s++) {
            if (wv < 3) {
                const s16x8 av = *(const s16x8*)&kt[(wv * 16 + lm) * 72 + s * 32 + lq * 8];
                #pragma unroll
                for (int ef = 0; ef < 3; ef++) {
                    const s16x8 bv = *(const s16x8*)&vt[(ef * 16 + lm) * 72 + s * 32 + lq * 8];
                    acc[ef] = __builtin_amdgcn_mfma_f32_16x16x32_bf16(av, bv, acc[ef], 0, 0, 0);
                }
            } else {
                #pragma unroll
                for (int mf = 0; mf < 3; mf++) {
                    const s16x8 av = *(const s16x8*)&kt[(mf * 16 + lm) * 72 + s * 32 + lq * 8];
                    acc[mf] = __builtin_amdgcn_mfma_f32_16x16x32_bf16(av, ones, acc[mf], 0, 0, 0);
                }
            }
        }
    }
    if (wv < 3) {
        #pragma unroll
        for (int ef = 0; ef < 3; ef++)
            #pragma unroll
            for (int r = 0; r < 4; r++)
                atomicAdd(&kv[(long)bh * 2304 + (wv * 16 + lq * 4 + r) * 48 + ef * 16 + lm], acc[ef][r]);
    } else {
        if (lm == 0) {
            #pragma unroll
            for (int mf = 0; mf < 3; mf++)
                #pragma unroll
                for (int r = 0; r < 4; r++)
                    atomicAdd(&ksum[bh * 48 + mf * 16 + lq * 4 + r], acc[mf][r]);
        }
    }
}

// kv f32 -> kv_pad bf16 [bh][e][64] (cols d, d>=48 zero); ksum -> [bh][64]
__global__ void repack_kv(const float* __restrict__ kvb, const float* __restrict__ ksb,
                          u16* __restrict__ kvp, u16* __restrict__ ksp)
{
    const int bh = blockIdx.x, t = threadIdx.x;
    for (int idx = t; idx < 3072; idx += 256) {
        const int e = idx >> 6, d = idx & 63;
        kvp[(long)bh * 3072 + idx] = (d < 48) ? f2bf(kvb[(long)bh * 2304 + d * 48 + e]) : (u16)0;
    }
    if (t < 64) ksp[bh * 64 + t] = (t < 48) ? f2bf(ksb[bh * 48 + t]) : (u16)0;
}

// ---------------------------------------------------------------------------
// MFMA attn stage 2: out[n][h*48+e] = (Q kv)[n][e] / (Q.ksum + eps).
// ---------------------------------------------------------------------------
__global__ __launch_bounds__(256) void attn_out_m(const u16* __restrict__ qk,
                                                  const u16* __restrict__ kvp,
                                                  const u16* __restrict__ ksp,
                                                  u16* __restrict__ outb)
{
    __shared__ __align__(16) u16 smem[4 * 7168];
    const int mt = blockIdx.x, hh = blockIdx.y, b = blockIdx.z;
    const int t = threadIdx.x, wv = t >> 6, ln = t & 63, lm = ln & 15, lq = ln >> 4;
    const int h = hh * 4 + wv, bh = b * 8 + h;
    u16* As = smem + wv * 7168;
    u16* Bs = As + 4096;
    const u16* Ab = qk + ((long)b * NPIX + mt * 64) * 768 + h * HDIM;
    const u16* Bb = kvp + (long)bh * 3072;

    #pragma unroll
    for (int rg = 0; rg < 4; rg++)
        #pragma unroll
        for (int oh = 0; oh < 2; oh++)
            GLL16(Ab + (long)(rg * 16 + lm) * 768 + oh * 32 + lq * 8, As + (rg * 128 + oh * 64) * 8);
    #pragma unroll
    for (int rg = 0; rg < 3; rg++)
        #pragma unroll
        for (int oh = 0; oh < 2; oh++)
            GLL16(Bb + (rg * 16 + lm) * 64 + oh * 32 + lq * 8, Bs + (rg * 128 + oh * 64) * 8);

    s16x8 kz[2];
    kz[0] = *(const s16x8*)&ksp[bh * 64 + lq * 8];
    kz[1] = *(const s16x8*)&ksp[bh * 64 + 32 + lq * 8];

    __syncthreads();

    f32x4 acc[4][3] = {};
    f32x4 accz[4] = {};
    #pragma unroll
    for (int s = 0; s < 2; s++) {
        s16x8 av[4], bv[3];
        #pragma unroll
        for (int mf = 0; mf < 4; mf++)
            av[mf] = *(const s16x8*)&As[(mf * 128 + s * 64 + ln) * 8];
        #pragma unroll
        for (int nf = 0; nf < 3; nf++)
            bv[nf] = *(const s16x8*)&Bs[(nf * 128 + s * 64 + ln) * 8];
        #pragma unroll
        for (int mf = 0; mf < 4; mf++) {
            #pragma unroll
            for (int nf = 0; nf < 3; nf++)
                acc[mf][nf] = __builtin_amdgcn_mfma_f32_16x16x32_bf16(av[mf], bv[nf], acc[mf][nf], 0, 0, 0);
            accz[mf] = __builtin_amdgcn_mfma_f32_16x16x32_bf16(av[mf], kz[s], accz[mf], 0, 0, 0);
        }
    }

    u16* stg = As;
    #pragma unroll
    for (int mf = 0; mf < 4; mf++) {
        #pragma unroll
        for (int r = 0; r < 4; r++) {
            const float z = 1.f / (accz[mf][r] + 1e-6f);
            const int row = mf * 16 + lq * 4 + r;
            #pragma unroll
            for (int nf = 0; nf < 3; nf++)
                stg[row * 56 + nf * 16 + lm] = f2bf(acc[mf][nf][r] * z);
        }
    }
    __syncthreads();

    #pragma unroll
    for (int it = 0; it < 6; it++) {
        const int idx = it * 256 + t;
        const int row = idx / 24, c = idx % 24;
        const int sw = c / 6, c6 = c % 6;
        const s16x8 vvv = *(const s16x8*)&smem[sw * 7168 + row * 56 + c6 * 8];
        *(s16x8*)&outb[((long)b * NPIX + mt * 64 + row) * CDIM + hh * 192 + c * 8] = vvv;
    }
}

// ---------------------------------------------------------------------------
// LayerNorm over contiguous 384 channels (NHWC)
// ---------------------------------------------------------------------------
__global__ __launch_bounds__(256) void ln_k(const float* __restrict__ x2,
                                            const float* __restrict__ lw,
                                            const float* __restrict__ lb,
                                            u16* __restrict__ xn)
{
    const int row = blockIdx.x * 4 + (threadIdx.x >> 6);
    const int lane = threadIdx.x & 63;
    const float* rp = x2 + (long)row * CDIM;
    float2 v[3];
    float sum = 0.f, sq = 0.f;
    #pragma unroll
    for (int i = 0; i < 3; i++) {
        v[i] = *(const float2*)&rp[lane * 2 + i * 128];
        sum += v[i].x + v[i].y;
        sq = fmaf(v[i].x, v[i].x, fmaf(v[i].y, v[i].y, sq));
    }
    #pragma unroll
    for (int off = 1; off < 64; off <<= 1) {
        sum += __shfl_xor(sum, off);
        sq  += __shfl_xor(sq, off);
    }
    const float mu = sum * (1.f / CDIM);
    const float rs = rsqrtf(sq * (1.f / CDIM) - mu * mu + LN_EPS);
    u16* op = xn + (long)row * CDIM;
    #pragma unroll
    for (int i = 0; i < 3; i++) {
        const int c = lane * 2 + i * 128;
        op[c]     = f2bf((v[i].x - mu) * rs * lw[c] + lb[c]);
        op[c + 1] = f2bf((v[i].y - mu) * rs * lw[c + 1] + lb[c + 1]);
    }
}

// ---------------------------------------------------------------------------
// Prep kernels
// ---------------------------------------------------------------------------
__global__ void prep_bn_k(const float* __restrict__ w1, const float* __restrict__ b1,
                          const float* __restrict__ m1, const float* __restrict__ v1,
                          const float* __restrict__ w2, const float* __restrict__ b2,
                          const float* __restrict__ m2, const float* __restrict__ v2,
                          const float* __restrict__ db,
                          float* s1, float* t1, float* s2, float* t2)
{
    const int i = threadIdx.x;
    if (i < CDIM) {
        const float a = w1[i] * rsqrtf(v1[i] + BN_EPS);
        s1[i] = a; t1[i] = b1[i] - m1[i] * a;
        const float c = w2[i] * rsqrtf(v2[i] + BN_EPS);
        s2[i] = c; t2[i] = b2[i] - m2[i] * c + db[i] * c;
    }
}

__global__ __launch_bounds__(64) void prep_w_k(
    const float* __restrict__ cw1, const float* __restrict__ cb1,
    const float* __restrict__ cw2, const float* __restrict__ cb2,
    const float* __restrict__ s1, const float* __restrict__ t1,
    const float* __restrict__ s2, const float* __restrict__ t2,
    u16* __restrict__ w1e, float* __restrict__ b1e,
    u16* __restrict__ w2e, float* __restrict__ b2e)
{
    const int o = blockIdx.x;
    const bool sec = (o >= CDIM);
    const int oo = sec ? o - CDIM : o;
    const float* cw = sec ? cw2 : cw1;
    const float* cb = sec ? cb2 : cb1;
    const float* s  = sec ? s2  : s1;
    const float* tt = sec ? t2  : t1;
    u16* we = sec ? w2e : w1e;
    float* be = sec ? b2e : b1e;
    float part = 0.f;
    for (int i = threadIdx.x; i < CDIM; i += 64) {
        const float wv = cw[oo * CDIM + i];
        we[oo * CDIM + i] = f2bf(wv * s[i]);
        part += wv * tt[i];
    }
    for (int off = 32; off; off >>= 1) part += __shfl_down(part, off);
    if (threadIdx.x == 0) be[oo] = cb[oo] + part;
}

__global__ void cvt_k(const float* __restrict__ in, u16* __restrict__ out, int n)
{
    const int i = blockIdx.x * 256 + threadIdx.x;
    if (i < n) out[i] = f2bf(in[i]);
}

__global__ __launch_bounds__(256) void transcvt_k(const float* __restrict__ in,
                                                  u16* __restrict__ out, int R, int C)
{
    __shared__ float tile[64 * 65];
    const int c0 = blockIdx.x << 6, r0 = blockIdx.y << 6;
    const int t = threadIdx.x;
    for (int idx = t; idx < 4096; idx += 256) {
        const int rr = idx >> 6, cc = idx & 63;
        tile[rr * 65 + cc] = in[(long)(r0 + rr) * C + c0 + cc];
    }
    __syncthreads();
    for (int idx = t; idx < 4096; idx += 256) {
        const int cc = idx >> 6, rr = idx & 63;
        out[(long)(c0 + cc) * R + r0 + rr] = f2bf(tile[rr * 65 + cc]);
    }
}

__global__ void dwt_k(const float* __restrict__ dw, u16* __restrict__ o)
{
    const int i = blockIdx.x * 256 + threadIdx.x;
    if (i < 9 * CDIM) {
        const int c = i / 9, tap = i % 9;
        o[tap * CDIM + c] = f2bf(dw[i]);
    }
}

// ---------------------------------------------------------------------------
// Launch
// ---------------------------------------------------------------------------
extern "C" void kernel_launch(void* const* d_in, const int* in_sizes, int n_in,
                              void* d_out, int out_size, void* d_ws, size_t ws_size,
                              hipStream_t stream)
{
    const float* x      = (const float*)d_in[0];
    const float* bn1_w  = (const float*)d_in[1];
    const float* bn1_b  = (const float*)d_in[2];
    const float* bn1_m  = (const float*)d_in[3];
    const float* bn1_v  = (const float*)d_in[4];
    const float* cw1    = (const float*)d_in[5];
    const float* cb1    = (const float*)d_in[6];
    const float* dwW    = (const float*)d_in[7];
    const float* db     = (const float*)d_in[8];
    const float* bn2_w  = (const float*)d_in[9];
    const float* bn2_b  = (const float*)d_in[10];
    const float* bn2_m  = (const float*)d_in[11];
    const float* bn2_v  = (const float*)d_in[12];
    const float* cw2    = (const float*)d_in[13];
    const float* cb2    = (const float*)d_in[14];
    const float* qkv_w  = (const float*)d_in[15];
    const float* proj_w = (const float*)d_in[16];
    const float* proj_b = (const float*)d_in[17];
    const float* ln_w   = (const float*)d_in[18];
    const float* ln_b   = (const float*)d_in[19];
    const float* mlp_w1 = (const float*)d_in[20];
    const float* mlp_b1 = (const float*)d_in[21];
    const float* mlp_w2 = (const float*)d_in[22];
    const float* mlp_b2 = (const float*)d_in[23];
    float* outF = (float*)d_out;

    const long S = (long)NROW * CDIM;   // 9,633,792
    float* wsf = (float*)d_ws;

    float* x2_f  = wsf;                       // F0: x2 (born at proj)
    u16*   v_bf  = (u16*)wsf;                 // F0 during attention (v)
    float* x1_f  = wsf + S;                   // F1: x1 (dead after proj)
    u16*   hmid  = (u16*)(wsf + S);           // F1: mlp hidden half
    u16* ar   = (u16*)(wsf + 2 * S);
    u16* a0   = ar;                           // xh_bf -> x1_bf -> attn_bf -> xn_bf
    u16* a1   = ar + S;                       // h_bf -> qk_bf (spans a1..a2)
    u16* a2   = ar + 2 * S;                   // d_bf
    u16* wtb   = (u16*)(wsf + 3 * S + S / 2);
    u16* w1e   = wtb;
    u16* w2e   = w1e + CDIM * CDIM;
    u16* qkvw  = w2e + CDIM * CDIM;
    u16* projw = qkvw + 1152 * CDIM;
    u16* mw1t  = projw + CDIM * CDIM;
    u16* mw2t  = mw1t + CMID * CDIM;
    u16* dwt   = mw2t + CDIM * CMID;
    float* fb  = (float*)(dwt + 9 * CDIM);
    float* b1e = fb;
    float* b2e = b1e + CDIM;
    float* s1  = b2e + CDIM;
    float* t1  = s1 + CDIM;
    float* s2  = t1 + CDIM;
    float* t2  = s2 + CDIM;
    float* kvb = t2 + CDIM;                   // 64*48*48 f32
    float* ksb = kvb + 64 * HDIM * HDIM;      // 64*48 f32
    u16*   kvp = (u16*)(ksb + 64 * HDIM);     // 64*48*64 bf16
    u16*   ksp = kvp + 64 * 3072;             // 64*64 bf16

    // --- weight prep ---
    prep_bn_k<<<1, CDIM, 0, stream>>>(bn1_w, bn1_b, bn1_m, bn1_v,
                                      bn2_w, bn2_b, bn2_m, bn2_v, db, s1, t1, s2, t2);
    prep_w_k<<<2 * CDIM, 64, 0, stream>>>(cw1, cb1, cw2, cb2, s1, t1, s2, t2,
                                          w1e, b1e, w2e, b2e);
    cvt_k<<<(1152 * CDIM + 255) / 256, 256, 0, stream>>>(qkv_w, qkvw, 1152 * CDIM);
    cvt_k<<<(CDIM * CDIM + 255) / 256, 256, 0, stream>>>(proj_w, projw, CDIM * CDIM);
    transcvt_k<<<dim3(CMID / 64, CDIM / 64), 256, 0, stream>>>(mlp_w1, mw1t, CDIM, CMID);
    transcvt_k<<<dim3(CDIM / 64, CMID / 64), 256, 0, stream>>>(mlp_w2, mw2t, CMID, CDIM);
    dwt_k<<<(9 * CDIM + 255) / 256, 256, 0, stream>>>(dwW, dwt);

    // --- pipeline (all NHWC) ---
    nchw_to_bf<<<dim3(49, 6, 8), 256, 0, stream>>>(x, a0);
    // conv1: h = W1' x + b1'   -> a1 (bf16)
    gemm_mfma<0, true, 0, true, false, false, 64, false><<<dim3(6, 196), 256, 0, stream>>>(
        a0, w1e, a1, nullptr, nullptr, nullptr, b1e, CDIM, CDIM, 0);
    dwconv_nhwc<<<(int)((long)BB * NPIX * 48 / 256), 256, 0, stream>>>(a1, dwt, a2);
    // conv2: x1 = W2' d + b2' + x(bf16 res)  -> a0 (bf16, in-place over x) + x1_f
    gemm_mfma<0, true, 2, true, true, false, 64, false><<<dim3(6, 196), 256, 0, stream>>>(
        a2, w2e, a0, nullptr, x1_f, a0, b2e, CDIM, CDIM, 0);
    // fused qkv — q|k phi -> a1 (ld 768), v -> v_bf (ld 384)
    gemm_mfma<0, false, 0, true, false, false, 128, true><<<dim3(9, 196), 256, 0, stream>>>(
        a0, qkvw, a1, v_bf, nullptr, nullptr, nullptr, 1152, CDIM, 0);
    // attention (MFMA)
    hipMemsetAsync(kvb, 0, (size_t)(64 * HDIM * HDIM + 64 * HDIM) * sizeof(float), stream);
    attn_kv_m<<<dim3(8, 64), 256, 0, stream>>>(a1, v_bf, kvb, ksb);
    repack_kv<<<64, 256, 0, stream>>>(kvb, ksb, kvp, ksp);
    attn_out_m<<<dim3(49, 2, 8), 256, 0, stream>>>(a1, kvp, ksp, a0);
    // proj: x2 = Wp attn + pb + x1  (f32 direct)
    gemm_mfma<0, true, 1, false, true, false, 64, false><<<dim3(6, 196), 256, 0, stream>>>(
        a0, projw, nullptr, nullptr, x2_f, x1_f, proj_b, CDIM, CDIM, 0);
    // LN -> xn (bf16)
    ln_k<<<NROW / 4, 256, 0, stream>>>(x2_f, ln_w, ln_b, a0);
    // MLP in two M-halves; mlp2 writes d_out NCHW directly (+x2 residual)
    const long RH = (long)NROW / 2;   // 12544
    gemm_mfma<2, true, 0, true, false, false, 128, false><<<dim3(12, 98), 256, 0, stream>>>(
        a0, mw1t, hmid, nullptr, nullptr, nullptr, mlp_b1, CMID, CDIM, 0);
    gemm_mfma<0, true, 1, false, false, true, 64, false><<<dim3(6, 98), 256, 0, stream>>>(
        hmid, mw2t, nullptr, nullptr, outF, x2_f, mlp_b2, CDIM, CMID, 0);
    gemm_mfma<2, true, 0, true, false, false, 128, false><<<dim3(12, 98), 256, 0, stream>>>(
        a0 + RH * CDIM, mw1t, hmid, nullptr, nullptr, nullptr, mlp_b1, CMID, CDIM, 0);
    gemm_mfma<0, true, 1, false, false, true, 64, false><<<dim3(6, 98), 256, 0, stream>>>(
        hmid, mw2t, nullptr, nullptr, outF, x2_f + RH * CDIM, mlp_b2, CDIM, CMID, RH);
}